// Round 18
// baseline (344.272 us; speedup 1.0000x reference)
//
#include <hip/hip_runtime.h>
#include <hip/hip_bf16.h>
#include <cmath>

// ---------------- problem constants ----------------
constexpr int cB = 16;
constexpr int cN = 4096;
constexpr int cC = 256;

typedef __attribute__((ext_vector_type(8))) short short8;
typedef __attribute__((ext_vector_type(4))) float f32x4;

__device__ inline unsigned short bfr(float f) {
  __hip_bfloat16 h = __float2bfloat16(f);
  return *(unsigned short*)&h;
}
__device__ inline float u16tof(unsigned short u) {
  unsigned int v = ((unsigned int)u) << 16;
  return __builtin_bit_cast(float, v);
}

// ---------------- workspace layout (float units) — ~92.8 MB ----------------
constexpr size_t oWQB    = 0;                               // 256x256 bf16
constexpr size_t oW1B    = oWQB    + 32768;                 // 256x4096 bf16
constexpr size_t oW2B    = oW1B    + 524288;                // 256x1024 bf16
constexpr size_t oWKV1B  = oW2B    + 131072;
constexpr size_t oWKV2B  = oWKV1B  + 65536;
constexpr size_t oWPROJB = oWKV2B  + 65536;
constexpr size_t oINVSP  = oWPROJB + 65536;                 // 256 f32 (pad 1024)
constexpr size_t oKM1    = oINVSP  + 1024;
constexpr size_t oKV1M   = oKM1    + 4096;
constexpr size_t oKM2    = oKV1M   + 131072;
constexpr size_t oKV2M   = oKM2    + 4096;
constexpr size_t oKVP    = oKV2M   + 131072;                // 4x131072 f32 kmkv partials
constexpr size_t oKMP    = oKVP    + 524288;                // 4x4096 f32
constexpr size_t oQBUF   = oKMP    + 16384;                 // q bf16 (16.7M elems = 8388608 fu)
constexpr size_t oV1G    = oQBUF   + 8388608;               // bf16 16x256x256  (524288 fu)
constexpr size_t oV2G    = oV1G    + 524288;                // bf16 16x1024x256 (2097152 fu)
constexpr size_t oU      = oV2G    + 2097152;               // union, 10,485,760 fu
// phase 1:
constexpr size_t oP1     = oU;                              // 4x(4096x256) f32
constexpr size_t oX1B    = oU + 4194304;                    // bf16 4096x256
constexpr size_t oY1     = oU + 4456448;                    // bf16 4096x512
constexpr size_t oK1P    = oU;                              // bf16 4096x256, aliases P1 (dead)
// phase 2:
constexpr size_t oX2     = oU;                              // f32 16384x256
constexpr size_t oY2     = oU + 4194304;                    // bf16 16384x512
constexpr size_t oX2B    = oU + 8388608;                    // bf16 16384x256
constexpr size_t oK2P    = oU;                              // bf16 16384x256, aliases X2 (dead)
// phase 3: AB bf16 16x4096x512 @ oU
constexpr size_t oAB     = oU;

// ---------------- one mega weight-pack kernel ----------------
__global__ __launch_bounds__(256) void pack_all(
    const float* __restrict__ Wq,   const float* __restrict__ Wkv1,
    const float* __restrict__ Wkv2, const float* __restrict__ Wproj,
    const float* __restrict__ Wsr1, const float* __restrict__ Wsr2,
    const float* __restrict__ scale,
    __hip_bfloat16* WQB, __hip_bfloat16* WKV1B, __hip_bfloat16* WKV2B,
    __hip_bfloat16* WPROJB, __hip_bfloat16* W1B, __hip_bfloat16* W2B,
    float* inv_sp)
{
  int bid = blockIdx.x, tid = threadIdx.x;
  if (bid < 256) {
    int i = bid*256 + tid; WQB[i] = __float2bfloat16(Wq[i]);
  } else if (bid < 768) {
    int i = (bid-256)*256 + tid; WKV1B[i] = __float2bfloat16(Wkv1[i]);
  } else if (bid < 1280) {
    int i = (bid-768)*256 + tid; WKV2B[i] = __float2bfloat16(Wkv2[i]);
  } else if (bid < 1792) {
    int i = (bid-1280)*256 + tid; WPROJB[i] = __float2bfloat16(Wproj[i]);
  } else if (bid < 5888) {
    int i = (bid-1792)*256 + tid;          // ((co*16+p)*256+ci)
    int ci = i & 255, rest = i >> 8;
    int p = rest & 15, co = rest >> 4;
    W1B[i] = __float2bfloat16(Wsr1[((size_t)co*256 + ci)*16 + p]);
  } else if (bid < 6912) {
    int i = (bid-5888)*256 + tid;          // ((co*4+p)*256+ci)
    int ci = i & 255, rest = i >> 8;
    int p = rest & 3, co = rest >> 2;
    W2B[i] = __float2bfloat16(Wsr2[((size_t)co*256 + ci)*4 + p]);
  } else {
    float v = scale[tid];
    float sp = (v > 20.f) ? v : log1pf(expf(v));
    inv_sp[tid] = 1.f/sp;
  }
}

// ---------------- MFMA bf16 GEMM ----------------
// AMODE: 0 row-major A; 1/2 conv patch gather. ADT: 0 f32 A, 1 bf16 A.
// EPI: 0 C=acc+bias f32; 1 q-scatter f32; 2 C+=acc; 3 partial; 4 q-scatter bf16; 5 C=acc+bias bf16
template<int TM, int TN, int AMODE, int ADT, int EPI>
__global__ __launch_bounds__(256) void gmfma(
    const void* __restrict__ Asrc, const __hip_bfloat16* __restrict__ Bp,
    const float* __restrict__ bias, float* __restrict__ Cout,
    int M, int N, int K, int ldb)
{
  constexpr int APASS = TM/32, BPASS = TN/32;
  constexpr int WGM = (TM==128) ? 2 : ((TN==64) ? 2 : 1);
  constexpr int WGN = 4/WGM;
  constexpr int WM = TM/WGM, WN = TN/WGN;
  constexpr int FM = WM/16, FN = WN/16;
  __shared__ char smem[(TM+TN)*128];
  char* As = smem;
  char* Bs = smem + TM*128;
  const int tid  = threadIdx.x;
  const int row0 = blockIdx.x * TM;
  const int col0 = blockIdx.y * TN;
  const int kbase = blockIdx.z * K;
  const int kq = tid & 7, rl = tid >> 3;
  const int w = tid >> 6, lane = tid & 63;
  const int wr = (WGM==2) ? (w>>1) : 0;
  const int wc = (WGM==2) ? (w&1)  : w;

  f32x4 acc[FM][FN] = {};
  short8 aS[APASS], bS[BPASS];

  auto loadA = [&](int k0) {
    int ka = kbase + k0;
    #pragma unroll
    for (int p = 0; p < APASS; ++p) {
      int r = row0 + rl + p*32;
      const char* ap;
      if (AMODE == 0) {
        if (ADT == 0) ap = (const char*)((const float*)Asrc + (size_t)r*K + k0 + kq*8);
        else          ap = (const char*)((const __hip_bfloat16*)Asrc + (size_t)r*K + k0 + kq*8);
      } else if (AMODE == 1) {
        int b = r >> 8, mm = r & 255;
        int my = mm >> 4, mx = mm & 15;
        int ch = ka >> 8, ky = ch >> 2, kx = ch & 3;
        int tok = (4*my + ky)*64 + 4*mx + kx;
        ap = (const char*)((const float*)Asrc + ((size_t)(b*4096 + tok))*256 + (ka & 255) + kq*8);
      } else {
        int b = r >> 10, mm = r & 1023;
        int my = mm >> 5, mx = mm & 31;
        int ch = ka >> 8, ky = ch >> 1, kx = ch & 1;
        int tok = (2*my + ky)*64 + 2*mx + kx;
        ap = (const char*)((const float*)Asrc + ((size_t)(b*4096 + tok))*256 + (ka & 255) + kq*8);
      }
      if (ADT == 0) {
        float4 v0 = *(const float4*)ap;
        float4 v1 = *(const float4*)(ap + 16);
        short8 s;
        s[0] = (short)bfr(v0.x); s[1] = (short)bfr(v0.y);
        s[2] = (short)bfr(v0.z); s[3] = (short)bfr(v0.w);
        s[4] = (short)bfr(v1.x); s[5] = (short)bfr(v1.y);
        s[6] = (short)bfr(v1.z); s[7] = (short)bfr(v1.w);
        aS[p] = s;
      } else {
        aS[p] = *(const short8*)ap;
      }
    }
  };
  auto loadB = [&](int k0) {
    #pragma unroll
    for (int p = 0; p < BPASS; ++p) {
      int n = col0 + rl + p*32;
      bS[p] = *(const short8*)(Bp + (size_t)n*ldb + kbase + k0 + kq*8);
    }
  };

  loadA(0); loadB(0);
  for (int k0 = 0; k0 < K; k0 += 64) {
    #pragma unroll
    for (int p = 0; p < APASS; ++p) {
      int r = rl + p*32;
      *(short8*)(As + r*128 + ((kq*16) ^ ((r&7)<<4))) = aS[p];
    }
    #pragma unroll
    for (int p = 0; p < BPASS; ++p) {
      int n = rl + p*32;
      *(short8*)(Bs + n*128 + ((kq*16) ^ ((n&7)<<4))) = bS[p];
    }
    __syncthreads();
    if (k0 + 64 < K) { loadA(k0 + 64); loadB(k0 + 64); }
    #pragma unroll
    for (int ks = 0; ks < 2; ++ks) {
      short8 af[FM], bfv[FN];
      #pragma unroll
      for (int i = 0; i < FM; ++i) {
        int r = wr*WM + i*16 + (lane & 15);
        af[i] = *(const short8*)(As + r*128 + ((ks*64 + (lane>>4)*16) ^ ((r&7)<<4)));
      }
      #pragma unroll
      for (int j = 0; j < FN; ++j) {
        int n = wc*WN + j*16 + (lane & 15);
        bfv[j] = *(const short8*)(Bs + n*128 + ((ks*64 + (lane>>4)*16) ^ ((n&7)<<4)));
      }
      #pragma unroll
      for (int i = 0; i < FM; ++i)
        #pragma unroll
        for (int j = 0; j < FN; ++j)
          acc[i][j] = __builtin_amdgcn_mfma_f32_16x16x32_bf16(af[i], bfv[j], acc[i][j], 0, 0, 0);
    }
    __syncthreads();
  }

  #pragma unroll
  for (int i = 0; i < FM; ++i) {
    #pragma unroll
    for (int j = 0; j < FN; ++j) {
      int cc = col0 + wc*WN + j*16 + (lane & 15);
      float bval = (EPI == 2 || EPI == 3) ? 0.f : bias[cc];
      #pragma unroll
      for (int rg = 0; rg < 4; ++rg) {
        int rr = row0 + wr*WM + i*16 + (lane>>4)*4 + rg;
        float v = acc[i][j][rg] + bval;
        if (EPI == 0) {
          Cout[(size_t)rr*N + cc] = v;
        } else if (EPI == 1) {
          int b = rr >> 12, n = rr & 4095;
          int h = cc >> 5, d = cc & 31;
          Cout[((size_t)(b*4096 + h*512 + (n >> 3)))*256 + (n & 7)*32 + d] = v;
        } else if (EPI == 2) {
          Cout[(size_t)rr*N + cc] += v;
        } else if (EPI == 3) {
          Cout[(size_t)blockIdx.z*((size_t)M*N) + (size_t)rr*N + cc] = v;
        } else if (EPI == 4) {
          int b = rr >> 12, n = rr & 4095;
          int h = cc >> 5, d = cc & 31;
          ((__hip_bfloat16*)Cout)[((size_t)(b*4096 + h*512 + (n >> 3)))*256 + (n & 7)*32 + d] =
              __float2bfloat16(v);
        } else {
          ((__hip_bfloat16*)Cout)[(size_t)rr*N + cc] = __float2bfloat16(v);
        }
      }
    }
  }
}

// ---------------- bf16 row powernorm (RMW, f32 math) ----------------
__global__ __launch_bounds__(256) void row_powernorm_bf(__hip_bfloat16* __restrict__ x,
    const float* __restrict__ inv_sp, int rows)
{
  int row = blockIdx.x*4 + (threadIdx.x >> 6);
  if (row >= rows) return;
  int lane = threadIdx.x & 63;
  __hip_bfloat16* p = x + (size_t)row*256 + lane*4;
  ushort4 u = *(ushort4*)p;
  const float4 is = *(const float4*)(inv_sp + lane*4);
  float r0 = (fmaxf(u16tof(u.x),0.f)+1e-6f)*is.x;
  float r1 = (fmaxf(u16tof(u.y),0.f)+1e-6f)*is.y;
  float r2 = (fmaxf(u16tof(u.z),0.f)+1e-6f)*is.z;
  float r3 = (fmaxf(u16tof(u.w),0.f)+1e-6f)*is.w;
  float s2 = r0*r0+r1*r1+r2*r2+r3*r3;
  #pragma unroll
  for (int o = 1; o < 64; o <<= 1) s2 += __shfl_xor(s2, o, 64);
  float c0 = r0*r0*r0, c1 = r1*r1*r1, c2 = r2*r2*r2, c3 = r3*r3*r3;
  float s6 = c0*c0+c1*c1+c2*c2+c3*c3;
  #pragma unroll
  for (int o = 1; o < 64; o <<= 1) s6 += __shfl_xor(s6, o, 64);
  float f = sqrtf(s2/s6);
  ushort4 w;
  w.x = bfr(c0*f); w.y = bfr(c1*f); w.z = bfr(c2*f); w.w = bfr(c3*f);
  *(ushort4*)p = w;
}

// ---------------- sum 4 split-K partials + bias, LayerNorm + GELU -> bf16 ----------------
__global__ __launch_bounds__(256) void ln_gelu_sum4(const float* __restrict__ P,
    const float* __restrict__ bias, const float* __restrict__ g, const float* __restrict__ bb,
    __hip_bfloat16* __restrict__ outb, int rows)
{
  const size_t PS = (size_t)rows*256;
  int row = blockIdx.x*4 + (threadIdx.x >> 6);
  if (row >= rows) return;
  int lane = threadIdx.x & 63;
  const float* p = P + (size_t)row*256 + lane*4;
  float4 v0 = *(const float4*)p;
  float4 v1 = *(const float4*)(p + PS);
  float4 v2 = *(const float4*)(p + 2*PS);
  float4 v3 = *(const float4*)(p + 3*PS);
  float4 bsv = *(const float4*)(bias + lane*4);
  float4 v;
  v.x = v0.x+v1.x+v2.x+v3.x+bsv.x;
  v.y = v0.y+v1.y+v2.y+v3.y+bsv.y;
  v.z = v0.z+v1.z+v2.z+v3.z+bsv.z;
  v.w = v0.w+v1.w+v2.w+v3.w+bsv.w;
  float s = v.x+v.y+v.z+v.w;
  #pragma unroll
  for (int o = 1; o < 64; o <<= 1) s += __shfl_xor(s, o, 64);
  float mu = s*(1.f/256.f);
  float d0 = v.x-mu, d1 = v.y-mu, d2 = v.z-mu, d3 = v.w-mu;
  float q = d0*d0+d1*d1+d2*d2+d3*d3;
  #pragma unroll
  for (int o = 1; o < 64; o <<= 1) q += __shfl_xor(q, o, 64);
  float rstd = rsqrtf(q*(1.f/256.f) + 1e-5f);
  float4 gv = *(const float4*)(g + lane*4);
  float4 bv = *(const float4*)(bb + lane*4);
  float y0 = d0*rstd*gv.x + bv.x;
  float y1 = d1*rstd*gv.y + bv.y;
  float y2 = d2*rstd*gv.z + bv.z;
  float y3 = d3*rstd*gv.w + bv.w;
  const float k = 0.70710678118654752f;
  ushort4 u;
  u.x = bfr(0.5f*y0*(1.f+erff(y0*k)));
  u.y = bfr(0.5f*y1*(1.f+erff(y1*k)));
  u.z = bfr(0.5f*y2*(1.f+erff(y2*k)));
  u.w = bfr(0.5f*y3*(1.f+erff(y3*k)));
  *(ushort4*)(outb + (size_t)row*256 + lane*4) = u;
}

// ---------------- LayerNorm + exact GELU: f32 in, bf16 out ----------------
__global__ __launch_bounds__(256) void ln_gelu_b(const float* __restrict__ x,
    const float* __restrict__ g, const float* __restrict__ bb,
    __hip_bfloat16* __restrict__ outb, int rows)
{
  int row = blockIdx.x*4 + (threadIdx.x >> 6);
  if (row >= rows) return;
  int lane = threadIdx.x & 63;
  const float* p = x + (size_t)row*256 + lane*4;
  float4 v = *(const float4*)p;
  float s = v.x+v.y+v.z+v.w;
  #pragma unroll
  for (int o = 1; o < 64; o <<= 1) s += __shfl_xor(s, o, 64);
  float mu = s*(1.f/256.f);
  float d0 = v.x-mu, d1 = v.y-mu, d2 = v.z-mu, d3 = v.w-mu;
  float q = d0*d0+d1*d1+d2*d2+d3*d3;
  #pragma unroll
  for (int o = 1; o < 64; o <<= 1) q += __shfl_xor(q, o, 64);
  float rstd = rsqrtf(q*(1.f/256.f) + 1e-5f);
  float4 gv = *(const float4*)(g + lane*4);
  float4 bv = *(const float4*)(bb + lane*4);
  float y0 = d0*rstd*gv.x + bv.x;
  float y1 = d1*rstd*gv.y + bv.y;
  float y2 = d2*rstd*gv.z + bv.z;
  float y3 = d3*rstd*gv.w + bv.w;
  const float k = 0.70710678118654752f;
  ushort4 u;
  u.x = bfr(0.5f*y0*(1.f+erff(y0*k)));
  u.y = bfr(0.5f*y1*(1.f+erff(y1*k)));
  u.z = bfr(0.5f*y2*(1.f+erff(y2*k)));
  u.w = bfr(0.5f*y3*(1.f+erff(y3*k)));
  *(ushort4*)(outb + (size_t)row*256 + lane*4) = u;
}

// ---------------- fused k+v gather (bf16 in/out, f32 LDS tiles) ----------------
template<int BR>
__global__ __launch_bounds__(256) void gather_kv2(const __hip_bfloat16* __restrict__ y,
    const float* __restrict__ pe, __hip_bfloat16* __restrict__ Ko, __hip_bfloat16* __restrict__ Vo)
{
  constexpr int NKV = (BR == 1) ? 256 : 1024;
  __shared__ float tk[64][65];
  __shared__ float tv[64][65];
  int bid = blockIdx.x;
  int cb = bid & 3;
  int nb = (bid >> 2) % (NKV/64);
  int b  = (bid >> 2) / (NKV/64);
  int n0 = nb*64, c0 = cb*64;
  int tid = threadIdx.x;
  #pragma unroll
  for (int pass = 0; pass < 16; ++pass) {
    int c_l = (tid >> 6)*16 + pass;
    int c = c0 + c_l;
    if (BR == 1) {
      int n_l = tid & 63;
      size_t base = ((size_t)(b*256 + c))*512 + 2*(n0 + n_l);
      tk[c_l][n_l] = __bfloat162float(y[base]);
      tv[c_l][n_l] = __bfloat162float(y[base + 1]);
    } else {
      int u = tid & 31, pp = (tid >> 5) & 1;
      int n_l = 2*u + pp;
      size_t rk = ((size_t)(b*1024 + pp*512 + c))*512 + (size_t)((n0 >> 1) + u);
      tk[c_l][n_l] = __bfloat162float(y[rk]);
      tv[c_l][n_l] = __bfloat162float(y[rk + (size_t)256*512]);
    }
  }
  __syncthreads();
  #pragma unroll
  for (int pass = 0; pass < 16; ++pass) {
    int n_l = (tid >> 6)*16 + pass;
    int c_l = tid & 63;
    int n = n0 + n_l, c = c0 + c_l;
    size_t o = ((size_t)(b*NKV + n))*256 + c;
    Ko[o] = __float2bfloat16(tk[c_l][n_l] + pe[n*256 + c]);
    Vo[o] = __float2bfloat16(tv[c_l][n_l]);
  }
}

// ---------------- kmkv split-N partials (bf16 inputs) ----------------
__global__ __launch_bounds__(256) void kmkv_part(const __hip_bfloat16* __restrict__ kp,
    const __hip_bfloat16* __restrict__ vg, float* __restrict__ kmp, float* __restrict__ kvp, int nkv)
{
  int g = blockIdx.x;
  int ch = g & 3, bh = g >> 2;
  int b = bh >> 3, h = bh & 7;
  int nchunk = nkv >> 2;
  int tid = threadIdx.x;
  __shared__ float ks[64][32];
  __shared__ float vs[64][32];
  int d  = tid >> 3;
  int e0 = (tid & 7)*4;
  float acc[4] = {0.f,0.f,0.f,0.f};
  float kmacc = 0.f;
  for (int n0 = ch*nchunk; n0 < (ch+1)*nchunk; n0 += 64) {
    #pragma unroll
    for (int i = 0; i < 2; ++i) {
      int f = tid + i*256;
      int nn = f >> 3, q4 = (f & 7)*4;
      size_t base = ((size_t)(b*nkv + n0 + nn))*256 + h*32 + q4;
      ushort4 ku = *(const ushort4*)(kp + base);
      ushort4 vu = *(const ushort4*)(vg + base);
      float4 kf, vf;
      kf.x = u16tof(ku.x); kf.y = u16tof(ku.y); kf.z = u16tof(ku.z); kf.w = u16tof(ku.w);
      vf.x = u16tof(vu.x); vf.y = u16tof(vu.y); vf.z = u16tof(vu.z); vf.w = u16tof(vu.w);
      *(float4*)&ks[nn][q4] = kf;
      *(float4*)&vs[nn][q4] = vf;
    }
    __syncthreads();
    #pragma unroll 8
    for (int nn = 0; nn < 64; ++nn) {
      float kd = ks[nn][d];
      kmacc += kd;
      #pragma unroll
      for (int j = 0; j < 4; ++j) acc[j] += kd * vs[nn][e0+j];
    }
    __syncthreads();
  }
  const float s2c = 1.0f/4096.0f;
  #pragma unroll
  for (int j = 0; j < 4; ++j)
    kvp[(size_t)ch*131072 + ((size_t)bh*32 + e0 + j)*32 + d] = acc[j]*s2c;
  if ((tid & 7) == 0) kmp[ch*4096 + bh*32 + d] = kmacc;
}

__global__ __launch_bounds__(256) void kmkv_red(const float* __restrict__ kmp,
    const float* __restrict__ kvp, float* __restrict__ km, float* __restrict__ kvm, float inv_nkv)
{
  int idx = blockIdx.x*256 + threadIdx.x;   // 131072
  kvm[idx] = kvp[idx] + kvp[131072 + idx] + kvp[262144 + idx] + kvp[393216 + idx];
  if (idx < 4096)
    km[idx] = (kmp[idx] + kmp[4096 + idx] + kmp[8192 + idx] + kmp[12288 + idx]) * inv_nkv;
}

// ---------------- MFMA attention v3 (proven) ----------------
__global__ __launch_bounds__(512) void attn_mfma(const __hip_bfloat16* __restrict__ q,
    const float* __restrict__ inv_sp,
    const float* __restrict__ km1, const float* __restrict__ kv1,
    const float* __restrict__ km2, const float* __restrict__ kv2,
    __hip_bfloat16* __restrict__ A)
{
  __shared__ __align__(16) char qs[64*512];
  __shared__ __align__(16) char kvs[32*512];
  __shared__ float zsf[2*64*8];   // [br][t_l][h]
  const int bid = blockIdx.x;
  const int b = bid >> 6, t0 = (bid & 63)*64;
  const int tid = threadIdx.x;

  {
    const float* src = kv1 + (size_t)b*8192;
    for (int i = tid; i < 8192; i += 512) {
      int h = i >> 10, e = (i >> 5) & 31, d = i & 31;
      *(unsigned short*)(kvs + e*512 + ((h*64 + d*2) ^ ((e&7)<<4))) = bfr(src[i]);
    }
  }

  {
    const int h = tid & 7;
    const int t_l = tid >> 3;
    const float* km1p = km1 + b*256 + h*32;
    const float* km2p = km2 + b*256 + h*32;
    const __hip_bfloat16* qp = q + ((size_t)(b*4096 + t0 + t_l))*256 + h*32;
    float cf[32];
    float s2 = 0.f, s6 = 0.f;
    #pragma unroll
    for (int j = 0; j < 4; ++j) {
      short8 qv = *(const short8*)(qp + j*8);
      float4 is0 = *(const float4*)(inv_sp + h*32 + j*8);
      float4 is1 = *(const float4*)(inv_sp + h*32 + j*8 + 4);
      float isv[8] = {is0.x, is0.y, is0.z, is0.w, is1.x, is1.y, is1.z, is1.w};
      #pragma unroll
      for (int k = 0; k < 8; ++k) {
        float val = u16tof((unsigned short)qv[k]);
        float r = (fmaxf(val, 0.f) + 1e-6f) * isv[k];
        s2 += r*r;
        float c = r*r*r;
        s6 += c*c;
        cf[j*8 + k] = c;
      }
    }
    #pragma unroll
    for (int o = 1; o < 8; o <<= 1) {
      s2 += __shfl_xor(s2, o, 64);
      s6 += __shfl_xor(s6, o, 64);
    }
    float f = sqrtf(s2/s6);
    float d1 = 0.f, d2 = 0.f;
    #pragma unroll
    for (int j = 0; j < 8; ++j) {
      float4 k1 = *(const float4*)(km1p + j*4);
      float4 k2 = *(const float4*)(km2p + j*4);
      float q0 = cf[4*j+0]*f, q1 = cf[4*j+1]*f, q2 = cf[4*j+2]*f, q3 = cf[4*j+3]*f;
      cf[4*j+0] = q0; cf[4*j+1] = q1; cf[4*j+2] = q2; cf[4*j+3] = q3;
      d1 += q0*k1.x + q1*k1.y + q2*k1.z + q3*k1.w;
      d2 += q0*k2.x + q1*k2.y + q2*k2.z + q3*k2.w;
    }
    zsf[0*512 + t_l*8 + h] = 1.0f/(d1 + 1e-6f);
    zsf[1*512 + t_l*8 + h] = 1.0f/(d2 + 1e-6f);
    #pragma unroll
    for (int j = 0; j < 4; ++j) {
      short8 s;
      #pragma unroll
      for (int k = 0; k < 8; ++k) s[k] = (short)bfr(cf[j*8+k]);
      *(short8*)(qs + t_l*512 + ((h*64 + j*16) ^ ((t_l&7)<<4))) = s;
    }
  }
  __syncthreads();

  const int h = tid >> 6, l = tid & 63;
  const int lr = l & 15, lk = l >> 4;
  #pragma unroll
  for (int br = 0; br < 2; ++br) {
    if (br == 1) {
      __syncthreads();
      const float* src = kv2 + (size_t)b*8192;
      for (int i = tid; i < 8192; i += 512) {
        int hh = i >> 10, e = (i >> 5) & 31, d = i & 31;
        *(unsigned short*)(kvs + e*512 + ((hh*64 + d*2) ^ ((e&7)<<4))) = bfr(src[i]);
      }
      __syncthreads();
    }
    #pragma unroll
    for (int tt = 0; tt < 4; ++tt) {
      int tr = tt*16 + lr;
      short8 af = *(const short8*)(qs + tr*512 + ((h*64 + lk*16) ^ ((tr&7)<<4)));
      #pragma unroll
      for (int eb = 0; eb < 2; ++eb) {
        int e = eb*16 + lr;
        short8 bf = *(const short8*)(kvs + e*512 + ((h*64 + lk*16) ^ ((e&7)<<4)));
        f32x4 acc = {0.f, 0.f, 0.f, 0.f};
        acc = __builtin_amdgcn_mfma_f32_16x16x32_bf16(af, bf, acc, 0, 0, 0);
        #pragma unroll
        for (int rg = 0; rg < 4; ++rg) {
          int row = lk*4 + rg;
          float z = zsf[br*512 + (tt*16 + row)*8 + h];
          A[((size_t)(b*4096 + t0 + tt*16 + row))*512 + br*256 + h*32 + e] =
              __float2bfloat16(acc[rg]*z);
        }
      }
    }
  }
}

// ---------------- fused interp + 5x5 dwconv v4: 8 output rows/block, bf16 LDS ----------------
template<int BR>
__global__ __launch_bounds__(256) void dwconv_f4(const __hip_bfloat16* __restrict__ vg,
    const float* __restrict__ Wd, const float* __restrict__ bias,
    __hip_bfloat16* __restrict__ A, int broff)
{
  constexpr int L    = (BR == 1) ? 256 : 1024;
  constexpr int RPSH = (BR == 1) ? 5 : 7;
  __shared__ unsigned short lds16[12*2048];   // 48 KB
  int wg = blockIdx.x;                    // 1024 blocks
  int wid = (wg & 7)*128 + (wg >> 3);     // XCD-chunked (bijective: 1024 = 8*128)
  int yt = wid & 7;
  int be = wid >> 3;
  int y0 = yt*8;
  int b = be >> 3, e = be & 7;
  int tid = threadIdx.x;

  // ---- stage 12 interp'd rows as bf16 (slot s <-> yy = y0 + s - 2) ----
  {
    int d0 = (tid & 7)*4;
    #pragma unroll
    for (int c = 0; c < 2; ++c) {
      int xs = c*32 + (tid >> 3);
      int xg = xs >> 3, xl = xs & 7;
      #pragma unroll
      for (int r = 0; r < 12; ++r) {
        int yy = y0 + r - 2;
        if (yy < 0 || yy > 63) continue;
        int t = e*512 + yy*8 + xg;
        float cpos = ((float)t + 0.5f) * ((float)L / 4096.0f) - 0.5f;
        cpos = fminf(fmaxf(cpos, 0.0f), (float)(L-1));
        int i0 = (int)cpos;
        float w = cpos - (float)i0;
        int i1 = (i0 + 1 < L) ? i0 + 1 : L - 1;
        int n0 = ((i0 & ((L/8)-1)) << 3) + xl, ch0 = ((i0 >> RPSH) << 5) + d0;
        int n1 = ((i1 & ((L/8)-1)) << 3) + xl, ch1 = ((i1 >> RPSH) << 5) + d0;
        ushort4 au = *(const ushort4*)(vg + ((size_t)(b*L + n0))*256 + ch0);
        ushort4 bu = *(const ushort4*)(vg + ((size_t)(b*L + n1))*256 + ch1);
        float ax = u16tof(au.x), ay = u16tof(au.y), az = u16tof(au.z), aw = u16tof(au.w);
        ushort4 o;
        o.x = bfr(ax + (u16tof(bu.x) - ax)*w);
        o.y = bfr(ay + (u16tof(bu.y) - ay)*w);
        o.z = bfr(az + (u16tof(bu.z) - az)*w);
        o.w = bfr(aw + (u16tof(bu.w) - aw)*w);
        *(ushort4*)(lds16 + r*2048 + xs*32 + d0) = o;
      }
    }
  }
  __syncthreads();

  // ---- compute 8 output rows (proven tap loop; bf16 LDS reads) ----
  int d = tid & 31, xg = tid >> 5;
  float w[25];
  #pragma unroll
  for (int i = 0; i < 25; ++i) w[i] = Wd[d*25 + i];
  float bv = bias[d];
  #pragma unroll
  for (int rr = 0; rr < 8; ++rr) {
    int y = y0 + rr;
    float acc[8] = {};
    #pragma unroll
    for (int dy = 0; dy < 5; ++dy) {
      int yy = y + dy - 2;
      if (yy >= 0 && yy <= 63) {
        const unsigned short* rb = lds16 + (rr + dy)*2048 + d;
        float in[12];
        #pragma unroll
        for (int i = 0; i < 12; ++i) {
          int xx = xg*8 - 2 + i;
          in[i] = (xx < 0 || xx > 63) ? 0.f : u16tof(rb[xx*32]);
        }
        #pragma unroll
        for (int dx = 0; dx < 5; ++dx) {
          float ww = w[dy*5 + dx];
          #pragma unroll
          for (int j = 0; j < 8; ++j) acc[j] += ww * in[j + dx];
        }
      }
    }
    #pragma unroll
    for (int j = 0; j < 8; ++j) {
      size_t o = ((size_t)(b*4096 + y*64 + xg*8 + j))*512 + broff + e*32 + d;
      float cur = __bfloat162float(A[o]);
      A[o] = __float2bfloat16(cur + acc[j] + bv);
    }
  }
}

// ---------------- launcher ----------------
extern "C" void kernel_launch(void* const* d_in, const int* in_sizes, int n_in,
                              void* d_out, int out_size, void* d_ws, size_t ws_size,
                              hipStream_t stream)
{
  (void)in_sizes; (void)n_in; (void)out_size; (void)ws_size;
  const float* x     = (const float*)d_in[0];
  const float* Wq    = (const float*)d_in[1];
  const float* bq    = (const float*)d_in[2];
  const float* Wsr1  = (const float*)d_in[3];
  const float* bsr1  = (const float*)d_in[4];
  const float* g1    = (const float*)d_in[5];
  const float* b1    = (const float*)d_in[6];
  const float* Wsr2  = (const float*)d_in[7];
  const float* bsr2  = (const float*)d_in[8];
  const float* g2    = (const float*)d_in[9];
  const float* b2    = (const float*)d_in[10];
  const float* Wkv1  = (const float*)d_in[11];
  const float* bkv1  = (const float*)d_in[12];
  const float* Wkv2  = (const float*)d_in[13];
  const float* bkv2  = (const float*)d_in[14];
  const float* pe1   = (const float*)d_in[15];
  const float* pe2   = (const float*)d_in[16];
  const float* Wproj = (const float*)d_in[17];
  const float* bproj = (const float*)d_in[18];
  const float* Wdwc  = (const float*)d_in[19];
  const float* bdwc  = (const float*)d_in[20];
  const float* scale = (const float*)d_in[21];
  float* out = (float*)d_out;
  float* ws  = (float*)d_ws;
  dim3 blk(256);

  __hip_bfloat16* WQB    = (__hip_bfloat16*)(ws + oWQB);
  __hip_bfloat16* W1B    = (__hip_bfloat16*)(ws + oW1B);
  __hip_bfloat16* W2B    = (__hip_bfloat16*)(ws + oW2B);
  __hip_bfloat16* WKV1B  = (__hip_bfloat16*)(ws + oWKV1B);
  __hip_bfloat16* WKV2B  = (__hip_bfloat16*)(ws + oWKV2B);
  __hip_bfloat16* WPROJB = (__hip_bfloat16*)(ws + oWPROJB);
  __hip_bfloat16* X1B    = (__hip_bfloat16*)(ws + oX1B);
  __hip_bfloat16* X2B    = (__hip_bfloat16*)(ws + oX2B);
  __hip_bfloat16* AB     = (__hip_bfloat16*)(ws + oAB);
  __hip_bfloat16* QB     = (__hip_bfloat16*)(ws + oQBUF);
  __hip_bfloat16* Y1B    = (__hip_bfloat16*)(ws + oY1);
  __hip_bfloat16* Y2B    = (__hip_bfloat16*)(ws + oY2);
  __hip_bfloat16* K1P    = (__hip_bfloat16*)(ws + oK1P);
  __hip_bfloat16* K2P    = (__hip_bfloat16*)(ws + oK2P);
  __hip_bfloat16* V1G    = (__hip_bfloat16*)(ws + oV1G);
  __hip_bfloat16* V2G    = (__hip_bfloat16*)(ws + oV2G);

  // one mega pack launch
  pack_all<<<6913, blk, 0, stream>>>(Wq, Wkv1, Wkv2, Wproj, Wsr1, Wsr2, scale,
      WQB, WKV1B, WKV2B, WPROJB, W1B, W2B, ws + oINVSP);

  // q = x@Wq^T + bq -> bf16 scattered q
  gmfma<128,128,0,0,4><<<dim3(512,2), blk, 0, stream>>>(x, WQB, bq, (float*)QB, 65536, 256, 256, 256);

  // ---- branch 1 staging ----
  gmfma<64,64,1,0,3><<<dim3(64,4,4), blk, 0, stream>>>(x, W1B, bsr1, ws+oP1, 4096, 256, 1024, 4096);
  ln_gelu_sum4<<<1024, blk, 0, stream>>>(ws+oP1, bsr1, g1, b1, X1B, 4096);
  gmfma<64,64,0,1,5><<<dim3(64,8), blk, 0, stream>>>(X1B, WKV1B, bkv1, (float*)Y1B, 4096, 512, 256, 256);
  gather_kv2<1><<<256, blk, 0, stream>>>(Y1B, pe1, K1P, V1G);
  row_powernorm_bf<<<1024, blk, 0, stream>>>(K1P, ws+oINVSP, 4096);
  kmkv_part<<<512, blk, 0, stream>>>(K1P, V1G, ws+oKMP, ws+oKVP, 256);
  kmkv_red<<<512, blk, 0, stream>>>(ws+oKMP, ws+oKVP, ws+oKM1, ws+oKV1M, 1.0f/256.0f);

  // ---- branch 2 staging ----
  gmfma<64,64,2,0,0><<<dim3(256,4), blk, 0, stream>>>(x, W2B, bsr2, ws+oX2, 16384, 256, 1024, 1024);
  ln_gelu_b<<<4096, blk, 0, stream>>>(ws+oX2, g2, b2, X2B, 16384);
  gmfma<64,64,0,1,5><<<dim3(256,8), blk, 0, stream>>>(X2B, WKV2B, bkv2, (float*)Y2B, 16384, 512, 256, 256);
  gather_kv2<2><<<1024, blk, 0, stream>>>(Y2B, pe2, K2P, V2G);
  row_powernorm_bf<<<4096, blk, 0, stream>>>(K2P, ws+oINVSP, 16384);
  kmkv_part<<<512, blk, 0, stream>>>(K2P, V2G, ws+oKMP, ws+oKVP, 1024);
  kmkv_red<<<512, blk, 0, stream>>>(ws+oKMP, ws+oKVP, ws+oKM2, ws+oKV2M, 1.0f/1024.0f);

  // ---- MFMA attention v3 (bf16 q) -> AB[b,t,0:512] ----
  attn_mfma<<<1024, dim3(512), 0, stream>>>(QB, ws+oINVSP,
      ws+oKM1, ws+oKV1M, ws+oKM2, ws+oKV2M, AB);

  // ---- fused interp+dwconv per branch (8 rows/block, bf16 LDS) ----
  dwconv_f4<1><<<cB*8*8, blk, 0, stream>>>(V1G, Wdwc, bdwc, AB, 0);
  dwconv_f4<2><<<cB*8*8, blk, 0, stream>>>(V2G, Wdwc, bdwc, AB, 256);

  // ---- single fused projection: out = AB @ Wproj^T + bproj ----
  gmfma<128,128,0,1,0><<<dim3(512,2), blk, 0, stream>>>(AB, WPROJB, bproj, out, 65536, 256, 512, 512);
}

// Round 19
// 314.597 us; speedup vs baseline: 1.0943x; 1.0943x over previous
//
#include <hip/hip_runtime.h>
#include <hip/hip_bf16.h>
#include <cmath>

// ---------------- problem constants ----------------
constexpr int cB = 16;
constexpr int cN = 4096;
constexpr int cC = 256;

typedef __attribute__((ext_vector_type(8))) short short8;
typedef __attribute__((ext_vector_type(4))) float f32x4;

__device__ inline unsigned short bfr(float f) {
  __hip_bfloat16 h = __float2bfloat16(f);
  return *(unsigned short*)&h;
}
__device__ inline float u16tof(unsigned short u) {
  unsigned int v = ((unsigned int)u) << 16;
  return __builtin_bit_cast(float, v);
}

// ---------------- workspace layout (float units) — ~92.8 MB ----------------
constexpr size_t oWQB    = 0;                               // 256x256 bf16
constexpr size_t oW1B    = oWQB    + 32768;                 // 256x4096 bf16
constexpr size_t oW2B    = oW1B    + 524288;                // 256x1024 bf16
constexpr size_t oWKV1B  = oW2B    + 131072;
constexpr size_t oWKV2B  = oWKV1B  + 65536;
constexpr size_t oWPROJB = oWKV2B  + 65536;
constexpr size_t oINVSP  = oWPROJB + 65536;                 // 256 f32 (pad 1024)
constexpr size_t oKM1    = oINVSP  + 1024;
constexpr size_t oKV1M   = oKM1    + 4096;
constexpr size_t oKM2    = oKV1M   + 131072;
constexpr size_t oKV2M   = oKM2    + 4096;
constexpr size_t oKVP    = oKV2M   + 131072;                // 4x131072 f32 kmkv partials
constexpr size_t oKMP    = oKVP    + 524288;                // 4x4096 f32
constexpr size_t oQBUF   = oKMP    + 16384;                 // q bf16 (16.7M elems = 8388608 fu)
constexpr size_t oV1G    = oQBUF   + 8388608;               // bf16 16x256x256  (524288 fu)
constexpr size_t oV2G    = oV1G    + 524288;                // bf16 16x1024x256 (2097152 fu)
constexpr size_t oU      = oV2G    + 2097152;               // union, 10,485,760 fu
// phase 1:
constexpr size_t oP1     = oU;                              // 4x(4096x256) f32
constexpr size_t oX1B    = oU + 4194304;                    // bf16 4096x256
constexpr size_t oY1     = oU + 4456448;                    // bf16 4096x512
constexpr size_t oK1P    = oU;                              // bf16 4096x256, aliases P1 (dead)
// phase 2:
constexpr size_t oX2     = oU;                              // f32 16384x256
constexpr size_t oY2     = oU + 4194304;                    // bf16 16384x512
constexpr size_t oX2B    = oU + 8388608;                    // bf16 16384x256
constexpr size_t oK2P    = oU;                              // bf16 16384x256, aliases X2 (dead)
// phase 3: AB bf16 16x4096x512 @ oU
constexpr size_t oAB     = oU;

// ---------------- one mega weight-pack kernel ----------------
__global__ __launch_bounds__(256) void pack_all(
    const float* __restrict__ Wq,   const float* __restrict__ Wkv1,
    const float* __restrict__ Wkv2, const float* __restrict__ Wproj,
    const float* __restrict__ Wsr1, const float* __restrict__ Wsr2,
    const float* __restrict__ scale,
    __hip_bfloat16* WQB, __hip_bfloat16* WKV1B, __hip_bfloat16* WKV2B,
    __hip_bfloat16* WPROJB, __hip_bfloat16* W1B, __hip_bfloat16* W2B,
    float* inv_sp)
{
  int bid = blockIdx.x, tid = threadIdx.x;
  if (bid < 256) {
    int i = bid*256 + tid; WQB[i] = __float2bfloat16(Wq[i]);
  } else if (bid < 768) {
    int i = (bid-256)*256 + tid; WKV1B[i] = __float2bfloat16(Wkv1[i]);
  } else if (bid < 1280) {
    int i = (bid-768)*256 + tid; WKV2B[i] = __float2bfloat16(Wkv2[i]);
  } else if (bid < 1792) {
    int i = (bid-1280)*256 + tid; WPROJB[i] = __float2bfloat16(Wproj[i]);
  } else if (bid < 5888) {
    int i = (bid-1792)*256 + tid;          // ((co*16+p)*256+ci)
    int ci = i & 255, rest = i >> 8;
    int p = rest & 15, co = rest >> 4;
    W1B[i] = __float2bfloat16(Wsr1[((size_t)co*256 + ci)*16 + p]);
  } else if (bid < 6912) {
    int i = (bid-5888)*256 + tid;          // ((co*4+p)*256+ci)
    int ci = i & 255, rest = i >> 8;
    int p = rest & 3, co = rest >> 2;
    W2B[i] = __float2bfloat16(Wsr2[((size_t)co*256 + ci)*4 + p]);
  } else {
    float v = scale[tid];
    float sp = (v > 20.f) ? v : log1pf(expf(v));
    inv_sp[tid] = 1.f/sp;
  }
}

// ---------------- MFMA bf16 GEMM ----------------
// AMODE: 0 row-major A; 1/2 conv patch gather. ADT: 0 f32 A, 1 bf16 A.
// EPI: 0 C=acc+bias f32; 1 q-scatter f32; 2 C+=acc; 3 partial; 4 q-scatter bf16; 5 C=acc+bias bf16
template<int TM, int TN, int AMODE, int ADT, int EPI>
__global__ __launch_bounds__(256) void gmfma(
    const void* __restrict__ Asrc, const __hip_bfloat16* __restrict__ Bp,
    const float* __restrict__ bias, float* __restrict__ Cout,
    int M, int N, int K, int ldb)
{
  constexpr int APASS = TM/32, BPASS = TN/32;
  constexpr int WGM = (TM==128) ? 2 : ((TN==64) ? 2 : 1);
  constexpr int WGN = 4/WGM;
  constexpr int WM = TM/WGM, WN = TN/WGN;
  constexpr int FM = WM/16, FN = WN/16;
  __shared__ char smem[(TM+TN)*128];
  char* As = smem;
  char* Bs = smem + TM*128;
  const int tid  = threadIdx.x;
  const int row0 = blockIdx.x * TM;
  const int col0 = blockIdx.y * TN;
  const int kbase = blockIdx.z * K;
  const int kq = tid & 7, rl = tid >> 3;
  const int w = tid >> 6, lane = tid & 63;
  const int wr = (WGM==2) ? (w>>1) : 0;
  const int wc = (WGM==2) ? (w&1)  : w;

  f32x4 acc[FM][FN] = {};
  short8 aS[APASS], bS[BPASS];

  auto loadA = [&](int k0) {
    int ka = kbase + k0;
    #pragma unroll
    for (int p = 0; p < APASS; ++p) {
      int r = row0 + rl + p*32;
      const char* ap;
      if (AMODE == 0) {
        if (ADT == 0) ap = (const char*)((const float*)Asrc + (size_t)r*K + k0 + kq*8);
        else          ap = (const char*)((const __hip_bfloat16*)Asrc + (size_t)r*K + k0 + kq*8);
      } else if (AMODE == 1) {
        int b = r >> 8, mm = r & 255;
        int my = mm >> 4, mx = mm & 15;
        int ch = ka >> 8, ky = ch >> 2, kx = ch & 3;
        int tok = (4*my + ky)*64 + 4*mx + kx;
        ap = (const char*)((const float*)Asrc + ((size_t)(b*4096 + tok))*256 + (ka & 255) + kq*8);
      } else {
        int b = r >> 10, mm = r & 1023;
        int my = mm >> 5, mx = mm & 31;
        int ch = ka >> 8, ky = ch >> 1, kx = ch & 1;
        int tok = (2*my + ky)*64 + 2*mx + kx;
        ap = (const char*)((const float*)Asrc + ((size_t)(b*4096 + tok))*256 + (ka & 255) + kq*8);
      }
      if (ADT == 0) {
        float4 v0 = *(const float4*)ap;
        float4 v1 = *(const float4*)(ap + 16);
        short8 s;
        s[0] = (short)bfr(v0.x); s[1] = (short)bfr(v0.y);
        s[2] = (short)bfr(v0.z); s[3] = (short)bfr(v0.w);
        s[4] = (short)bfr(v1.x); s[5] = (short)bfr(v1.y);
        s[6] = (short)bfr(v1.z); s[7] = (short)bfr(v1.w);
        aS[p] = s;
      } else {
        aS[p] = *(const short8*)ap;
      }
    }
  };
  auto loadB = [&](int k0) {
    #pragma unroll
    for (int p = 0; p < BPASS; ++p) {
      int n = col0 + rl + p*32;
      bS[p] = *(const short8*)(Bp + (size_t)n*ldb + kbase + k0 + kq*8);
    }
  };

  loadA(0); loadB(0);
  for (int k0 = 0; k0 < K; k0 += 64) {
    #pragma unroll
    for (int p = 0; p < APASS; ++p) {
      int r = rl + p*32;
      *(short8*)(As + r*128 + ((kq*16) ^ ((r&7)<<4))) = aS[p];
    }
    #pragma unroll
    for (int p = 0; p < BPASS; ++p) {
      int n = rl + p*32;
      *(short8*)(Bs + n*128 + ((kq*16) ^ ((n&7)<<4))) = bS[p];
    }
    __syncthreads();
    if (k0 + 64 < K) { loadA(k0 + 64); loadB(k0 + 64); }
    #pragma unroll
    for (int ks = 0; ks < 2; ++ks) {
      short8 af[FM], bfv[FN];
      #pragma unroll
      for (int i = 0; i < FM; ++i) {
        int r = wr*WM + i*16 + (lane & 15);
        af[i] = *(const short8*)(As + r*128 + ((ks*64 + (lane>>4)*16) ^ ((r&7)<<4)));
      }
      #pragma unroll
      for (int j = 0; j < FN; ++j) {
        int n = wc*WN + j*16 + (lane & 15);
        bfv[j] = *(const short8*)(Bs + n*128 + ((ks*64 + (lane>>4)*16) ^ ((n&7)<<4)));
      }
      #pragma unroll
      for (int i = 0; i < FM; ++i)
        #pragma unroll
        for (int j = 0; j < FN; ++j)
          acc[i][j] = __builtin_amdgcn_mfma_f32_16x16x32_bf16(af[i], bfv[j], acc[i][j], 0, 0, 0);
    }
    __syncthreads();
  }

  #pragma unroll
  for (int i = 0; i < FM; ++i) {
    #pragma unroll
    for (int j = 0; j < FN; ++j) {
      int cc = col0 + wc*WN + j*16 + (lane & 15);
      float bval = (EPI == 2 || EPI == 3) ? 0.f : bias[cc];
      #pragma unroll
      for (int rg = 0; rg < 4; ++rg) {
        int rr = row0 + wr*WM + i*16 + (lane>>4)*4 + rg;
        float v = acc[i][j][rg] + bval;
        if (EPI == 0) {
          Cout[(size_t)rr*N + cc] = v;
        } else if (EPI == 1) {
          int b = rr >> 12, n = rr & 4095;
          int h = cc >> 5, d = cc & 31;
          Cout[((size_t)(b*4096 + h*512 + (n >> 3)))*256 + (n & 7)*32 + d] = v;
        } else if (EPI == 2) {
          Cout[(size_t)rr*N + cc] += v;
        } else if (EPI == 3) {
          Cout[(size_t)blockIdx.z*((size_t)M*N) + (size_t)rr*N + cc] = v;
        } else if (EPI == 4) {
          int b = rr >> 12, n = rr & 4095;
          int h = cc >> 5, d = cc & 31;
          ((__hip_bfloat16*)Cout)[((size_t)(b*4096 + h*512 + (n >> 3)))*256 + (n & 7)*32 + d] =
              __float2bfloat16(v);
        } else {
          ((__hip_bfloat16*)Cout)[(size_t)rr*N + cc] = __float2bfloat16(v);
        }
      }
    }
  }
}

// ---------------- bf16 row powernorm (RMW, f32 math) ----------------
__global__ __launch_bounds__(256) void row_powernorm_bf(__hip_bfloat16* __restrict__ x,
    const float* __restrict__ inv_sp, int rows)
{
  int row = blockIdx.x*4 + (threadIdx.x >> 6);
  if (row >= rows) return;
  int lane = threadIdx.x & 63;
  __hip_bfloat16* p = x + (size_t)row*256 + lane*4;
  ushort4 u = *(ushort4*)p;
  const float4 is = *(const float4*)(inv_sp + lane*4);
  float r0 = (fmaxf(u16tof(u.x),0.f)+1e-6f)*is.x;
  float r1 = (fmaxf(u16tof(u.y),0.f)+1e-6f)*is.y;
  float r2 = (fmaxf(u16tof(u.z),0.f)+1e-6f)*is.z;
  float r3 = (fmaxf(u16tof(u.w),0.f)+1e-6f)*is.w;
  float s2 = r0*r0+r1*r1+r2*r2+r3*r3;
  #pragma unroll
  for (int o = 1; o < 64; o <<= 1) s2 += __shfl_xor(s2, o, 64);
  float c0 = r0*r0*r0, c1 = r1*r1*r1, c2 = r2*r2*r2, c3 = r3*r3*r3;
  float s6 = c0*c0+c1*c1+c2*c2+c3*c3;
  #pragma unroll
  for (int o = 1; o < 64; o <<= 1) s6 += __shfl_xor(s6, o, 64);
  float f = sqrtf(s2/s6);
  ushort4 w;
  w.x = bfr(c0*f); w.y = bfr(c1*f); w.z = bfr(c2*f); w.w = bfr(c3*f);
  *(ushort4*)p = w;
}

// ---------------- sum 4 split-K partials + bias, LayerNorm + GELU -> bf16 ----------------
__global__ __launch_bounds__(256) void ln_gelu_sum4(const float* __restrict__ P,
    const float* __restrict__ bias, const float* __restrict__ g, const float* __restrict__ bb,
    __hip_bfloat16* __restrict__ outb, int rows)
{
  const size_t PS = (size_t)rows*256;
  int row = blockIdx.x*4 + (threadIdx.x >> 6);
  if (row >= rows) return;
  int lane = threadIdx.x & 63;
  const float* p = P + (size_t)row*256 + lane*4;
  float4 v0 = *(const float4*)p;
  float4 v1 = *(const float4*)(p + PS);
  float4 v2 = *(const float4*)(p + 2*PS);
  float4 v3 = *(const float4*)(p + 3*PS);
  float4 bsv = *(const float4*)(bias + lane*4);
  float4 v;
  v.x = v0.x+v1.x+v2.x+v3.x+bsv.x;
  v.y = v0.y+v1.y+v2.y+v3.y+bsv.y;
  v.z = v0.z+v1.z+v2.z+v3.z+bsv.z;
  v.w = v0.w+v1.w+v2.w+v3.w+bsv.w;
  float s = v.x+v.y+v.z+v.w;
  #pragma unroll
  for (int o = 1; o < 64; o <<= 1) s += __shfl_xor(s, o, 64);
  float mu = s*(1.f/256.f);
  float d0 = v.x-mu, d1 = v.y-mu, d2 = v.z-mu, d3 = v.w-mu;
  float q = d0*d0+d1*d1+d2*d2+d3*d3;
  #pragma unroll
  for (int o = 1; o < 64; o <<= 1) q += __shfl_xor(q, o, 64);
  float rstd = rsqrtf(q*(1.f/256.f) + 1e-5f);
  float4 gv = *(const float4*)(g + lane*4);
  float4 bv = *(const float4*)(bb + lane*4);
  float y0 = d0*rstd*gv.x + bv.x;
  float y1 = d1*rstd*gv.y + bv.y;
  float y2 = d2*rstd*gv.z + bv.z;
  float y3 = d3*rstd*gv.w + bv.w;
  const float k = 0.70710678118654752f;
  ushort4 u;
  u.x = bfr(0.5f*y0*(1.f+erff(y0*k)));
  u.y = bfr(0.5f*y1*(1.f+erff(y1*k)));
  u.z = bfr(0.5f*y2*(1.f+erff(y2*k)));
  u.w = bfr(0.5f*y3*(1.f+erff(y3*k)));
  *(ushort4*)(outb + (size_t)row*256 + lane*4) = u;
}

// ---------------- LayerNorm + exact GELU: f32 in, bf16 out ----------------
__global__ __launch_bounds__(256) void ln_gelu_b(const float* __restrict__ x,
    const float* __restrict__ g, const float* __restrict__ bb,
    __hip_bfloat16* __restrict__ outb, int rows)
{
  int row = blockIdx.x*4 + (threadIdx.x >> 6);
  if (row >= rows) return;
  int lane = threadIdx.x & 63;
  const float* p = x + (size_t)row*256 + lane*4;
  float4 v = *(const float4*)p;
  float s = v.x+v.y+v.z+v.w;
  #pragma unroll
  for (int o = 1; o < 64; o <<= 1) s += __shfl_xor(s, o, 64);
  float mu = s*(1.f/256.f);
  float d0 = v.x-mu, d1 = v.y-mu, d2 = v.z-mu, d3 = v.w-mu;
  float q = d0*d0+d1*d1+d2*d2+d3*d3;
  #pragma unroll
  for (int o = 1; o < 64; o <<= 1) q += __shfl_xor(q, o, 64);
  float rstd = rsqrtf(q*(1.f/256.f) + 1e-5f);
  float4 gv = *(const float4*)(g + lane*4);
  float4 bv = *(const float4*)(bb + lane*4);
  float y0 = d0*rstd*gv.x + bv.x;
  float y1 = d1*rstd*gv.y + bv.y;
  float y2 = d2*rstd*gv.z + bv.z;
  float y3 = d3*rstd*gv.w + bv.w;
  const float k = 0.70710678118654752f;
  ushort4 u;
  u.x = bfr(0.5f*y0*(1.f+erff(y0*k)));
  u.y = bfr(0.5f*y1*(1.f+erff(y1*k)));
  u.z = bfr(0.5f*y2*(1.f+erff(y2*k)));
  u.w = bfr(0.5f*y3*(1.f+erff(y3*k)));
  *(ushort4*)(outb + (size_t)row*256 + lane*4) = u;
}

// ---------------- fused k+v gather (bf16 in/out, f32 LDS tiles) ----------------
template<int BR>
__global__ __launch_bounds__(256) void gather_kv2(const __hip_bfloat16* __restrict__ y,
    const float* __restrict__ pe, __hip_bfloat16* __restrict__ Ko, __hip_bfloat16* __restrict__ Vo)
{
  constexpr int NKV = (BR == 1) ? 256 : 1024;
  __shared__ float tk[64][65];
  __shared__ float tv[64][65];
  int bid = blockIdx.x;
  int cb = bid & 3;
  int nb = (bid >> 2) % (NKV/64);
  int b  = (bid >> 2) / (NKV/64);
  int n0 = nb*64, c0 = cb*64;
  int tid = threadIdx.x;
  #pragma unroll
  for (int pass = 0; pass < 16; ++pass) {
    int c_l = (tid >> 6)*16 + pass;
    int c = c0 + c_l;
    if (BR == 1) {
      int n_l = tid & 63;
      size_t base = ((size_t)(b*256 + c))*512 + 2*(n0 + n_l);
      tk[c_l][n_l] = __bfloat162float(y[base]);
      tv[c_l][n_l] = __bfloat162float(y[base + 1]);
    } else {
      int u = tid & 31, pp = (tid >> 5) & 1;
      int n_l = 2*u + pp;
      size_t rk = ((size_t)(b*1024 + pp*512 + c))*512 + (size_t)((n0 >> 1) + u);
      tk[c_l][n_l] = __bfloat162float(y[rk]);
      tv[c_l][n_l] = __bfloat162float(y[rk + (size_t)256*512]);
    }
  }
  __syncthreads();
  #pragma unroll
  for (int pass = 0; pass < 16; ++pass) {
    int n_l = (tid >> 6)*16 + pass;
    int c_l = tid & 63;
    int n = n0 + n_l, c = c0 + c_l;
    size_t o = ((size_t)(b*NKV + n))*256 + c;
    Ko[o] = __float2bfloat16(tk[c_l][n_l] + pe[n*256 + c]);
    Vo[o] = __float2bfloat16(tv[c_l][n_l]);
  }
}

// ---------------- kmkv split-N partials (bf16 inputs) ----------------
__global__ __launch_bounds__(256) void kmkv_part(const __hip_bfloat16* __restrict__ kp,
    const __hip_bfloat16* __restrict__ vg, float* __restrict__ kmp, float* __restrict__ kvp, int nkv)
{
  int g = blockIdx.x;
  int ch = g & 3, bh = g >> 2;
  int b = bh >> 3, h = bh & 7;
  int nchunk = nkv >> 2;
  int tid = threadIdx.x;
  __shared__ float ks[64][32];
  __shared__ float vs[64][32];
  int d  = tid >> 3;
  int e0 = (tid & 7)*4;
  float acc[4] = {0.f,0.f,0.f,0.f};
  float kmacc = 0.f;
  for (int n0 = ch*nchunk; n0 < (ch+1)*nchunk; n0 += 64) {
    #pragma unroll
    for (int i = 0; i < 2; ++i) {
      int f = tid + i*256;
      int nn = f >> 3, q4 = (f & 7)*4;
      size_t base = ((size_t)(b*nkv + n0 + nn))*256 + h*32 + q4;
      ushort4 ku = *(const ushort4*)(kp + base);
      ushort4 vu = *(const ushort4*)(vg + base);
      float4 kf, vf;
      kf.x = u16tof(ku.x); kf.y = u16tof(ku.y); kf.z = u16tof(ku.z); kf.w = u16tof(ku.w);
      vf.x = u16tof(vu.x); vf.y = u16tof(vu.y); vf.z = u16tof(vu.z); vf.w = u16tof(vu.w);
      *(float4*)&ks[nn][q4] = kf;
      *(float4*)&vs[nn][q4] = vf;
    }
    __syncthreads();
    #pragma unroll 8
    for (int nn = 0; nn < 64; ++nn) {
      float kd = ks[nn][d];
      kmacc += kd;
      #pragma unroll
      for (int j = 0; j < 4; ++j) acc[j] += kd * vs[nn][e0+j];
    }
    __syncthreads();
  }
  const float s2c = 1.0f/4096.0f;
  #pragma unroll
  for (int j = 0; j < 4; ++j)
    kvp[(size_t)ch*131072 + ((size_t)bh*32 + e0 + j)*32 + d] = acc[j]*s2c;
  if ((tid & 7) == 0) kmp[ch*4096 + bh*32 + d] = kmacc;
}

__global__ __launch_bounds__(256) void kmkv_red(const float* __restrict__ kmp,
    const float* __restrict__ kvp, float* __restrict__ km, float* __restrict__ kvm, float inv_nkv)
{
  int idx = blockIdx.x*256 + threadIdx.x;   // 131072
  kvm[idx] = kvp[idx] + kvp[131072 + idx] + kvp[262144 + idx] + kvp[393216 + idx];
  if (idx < 4096)
    km[idx] = (kmp[idx] + kmp[4096 + idx] + kmp[8192 + idx] + kmp[12288 + idx]) * inv_nkv;
}

// ---------------- MFMA attention v3 (proven) ----------------
__global__ __launch_bounds__(512) void attn_mfma(const __hip_bfloat16* __restrict__ q,
    const float* __restrict__ inv_sp,
    const float* __restrict__ km1, const float* __restrict__ kv1,
    const float* __restrict__ km2, const float* __restrict__ kv2,
    __hip_bfloat16* __restrict__ A)
{
  __shared__ __align__(16) char qs[64*512];
  __shared__ __align__(16) char kvs[32*512];
  __shared__ float zsf[2*64*8];   // [br][t_l][h]
  const int bid = blockIdx.x;
  const int b = bid >> 6, t0 = (bid & 63)*64;
  const int tid = threadIdx.x;

  {
    const float* src = kv1 + (size_t)b*8192;
    for (int i = tid; i < 8192; i += 512) {
      int h = i >> 10, e = (i >> 5) & 31, d = i & 31;
      *(unsigned short*)(kvs + e*512 + ((h*64 + d*2) ^ ((e&7)<<4))) = bfr(src[i]);
    }
  }

  {
    const int h = tid & 7;
    const int t_l = tid >> 3;
    const float* km1p = km1 + b*256 + h*32;
    const float* km2p = km2 + b*256 + h*32;
    const __hip_bfloat16* qp = q + ((size_t)(b*4096 + t0 + t_l))*256 + h*32;
    float cf[32];
    float s2 = 0.f, s6 = 0.f;
    #pragma unroll
    for (int j = 0; j < 4; ++j) {
      short8 qv = *(const short8*)(qp + j*8);
      float4 is0 = *(const float4*)(inv_sp + h*32 + j*8);
      float4 is1 = *(const float4*)(inv_sp + h*32 + j*8 + 4);
      float isv[8] = {is0.x, is0.y, is0.z, is0.w, is1.x, is1.y, is1.z, is1.w};
      #pragma unroll
      for (int k = 0; k < 8; ++k) {
        float val = u16tof((unsigned short)qv[k]);
        float r = (fmaxf(val, 0.f) + 1e-6f) * isv[k];
        s2 += r*r;
        float c = r*r*r;
        s6 += c*c;
        cf[j*8 + k] = c;
      }
    }
    #pragma unroll
    for (int o = 1; o < 8; o <<= 1) {
      s2 += __shfl_xor(s2, o, 64);
      s6 += __shfl_xor(s6, o, 64);
    }
    float f = sqrtf(s2/s6);
    float d1 = 0.f, d2 = 0.f;
    #pragma unroll
    for (int j = 0; j < 8; ++j) {
      float4 k1 = *(const float4*)(km1p + j*4);
      float4 k2 = *(const float4*)(km2p + j*4);
      float q0 = cf[4*j+0]*f, q1 = cf[4*j+1]*f, q2 = cf[4*j+2]*f, q3 = cf[4*j+3]*f;
      cf[4*j+0] = q0; cf[4*j+1] = q1; cf[4*j+2] = q2; cf[4*j+3] = q3;
      d1 += q0*k1.x + q1*k1.y + q2*k1.z + q3*k1.w;
      d2 += q0*k2.x + q1*k2.y + q2*k2.z + q3*k2.w;
    }
    zsf[0*512 + t_l*8 + h] = 1.0f/(d1 + 1e-6f);
    zsf[1*512 + t_l*8 + h] = 1.0f/(d2 + 1e-6f);
    #pragma unroll
    for (int j = 0; j < 4; ++j) {
      short8 s;
      #pragma unroll
      for (int k = 0; k < 8; ++k) s[k] = (short)bfr(cf[j*8+k]);
      *(short8*)(qs + t_l*512 + ((h*64 + j*16) ^ ((t_l&7)<<4))) = s;
    }
  }
  __syncthreads();

  const int h = tid >> 6, l = tid & 63;
  const int lr = l & 15, lk = l >> 4;
  #pragma unroll
  for (int br = 0; br < 2; ++br) {
    if (br == 1) {
      __syncthreads();
      const float* src = kv2 + (size_t)b*8192;
      for (int i = tid; i < 8192; i += 512) {
        int hh = i >> 10, e = (i >> 5) & 31, d = i & 31;
        *(unsigned short*)(kvs + e*512 + ((hh*64 + d*2) ^ ((e&7)<<4))) = bfr(src[i]);
      }
      __syncthreads();
    }
    #pragma unroll
    for (int tt = 0; tt < 4; ++tt) {
      int tr = tt*16 + lr;
      short8 af = *(const short8*)(qs + tr*512 + ((h*64 + lk*16) ^ ((tr&7)<<4)));
      #pragma unroll
      for (int eb = 0; eb < 2; ++eb) {
        int e = eb*16 + lr;
        short8 bf = *(const short8*)(kvs + e*512 + ((h*64 + lk*16) ^ ((e&7)<<4)));
        f32x4 acc = {0.f, 0.f, 0.f, 0.f};
        acc = __builtin_amdgcn_mfma_f32_16x16x32_bf16(af, bf, acc, 0, 0, 0);
        #pragma unroll
        for (int rg = 0; rg < 4; ++rg) {
          int row = lk*4 + rg;
          float z = zsf[br*512 + (tt*16 + row)*8 + h];
          A[((size_t)(b*4096 + t0 + tt*16 + row))*512 + br*256 + h*32 + e] =
              __float2bfloat16(acc[rg]*z);
        }
      }
    }
  }
}

// ---------------- merged fused interp + 5x5 dwconv (both branches, one launch) ----------------
__global__ __launch_bounds__(256) void dwconv_f2m(const __hip_bfloat16* __restrict__ v1,
    const __hip_bfloat16* __restrict__ v2,
    const float* __restrict__ Wd, const float* __restrict__ bias,
    __hip_bfloat16* __restrict__ A)
{
  __shared__ float lds[6*2048];
  int bidx = blockIdx.x;                  // 8192 blocks: [0,4096) br1, [4096,8192) br2
  bool br2 = bidx >= 4096;
  int wg = br2 ? (bidx - 4096) : bidx;
  const __hip_bfloat16* vg = br2 ? v2 : v1;
  const int broff = br2 ? 256 : 0;
  const int L    = br2 ? 1024 : 256;
  const int RPSH = br2 ? 7 : 5;
  const int NM   = (L >> 3) - 1;          // (L/8)-1 mask
  const float sc = br2 ? 0.25f : 0.0625f; // L/4096
  const float lmax = (float)(L - 1);

  int wid = (wg & 7)*512 + (wg >> 3);     // XCD-chunked per branch half
  int yp = wid & 31;
  int be = wid >> 5;
  int y0 = yp*2;
  int b = be >> 3, e = be & 7;
  int tid = threadIdx.x;

  {
    int d0 = (tid & 7)*4;
    #pragma unroll
    for (int c = 0; c < 2; ++c) {
      int xs = c*32 + (tid >> 3);
      int xg = xs >> 3, xl = xs & 7;
      #pragma unroll
      for (int r = 0; r < 6; ++r) {
        int yy = y0 + r - 2;
        if (yy < 0 || yy > 63) continue;
        int t = e*512 + yy*8 + xg;
        float cpos = ((float)t + 0.5f) * sc - 0.5f;
        cpos = fminf(fmaxf(cpos, 0.0f), lmax);
        int i0 = (int)cpos;
        float w = cpos - (float)i0;
        int i1 = (i0 + 1 < L) ? i0 + 1 : L - 1;
        int n0 = ((i0 & NM) << 3) + xl, ch0 = ((i0 >> RPSH) << 5) + d0;
        int n1 = ((i1 & NM) << 3) + xl, ch1 = ((i1 >> RPSH) << 5) + d0;
        ushort4 au = *(const ushort4*)(vg + ((size_t)(b*L + n0))*256 + ch0);
        ushort4 bu = *(const ushort4*)(vg + ((size_t)(b*L + n1))*256 + ch1);
        float4 o;
        float ax = u16tof(au.x), ay = u16tof(au.y), az = u16tof(au.z), aw = u16tof(au.w);
        o.x = ax + (u16tof(bu.x) - ax)*w;
        o.y = ay + (u16tof(bu.y) - ay)*w;
        o.z = az + (u16tof(bu.z) - az)*w;
        o.w = aw + (u16tof(bu.w) - aw)*w;
        *(float4*)(lds + r*2048 + xs*32 + d0) = o;
      }
    }
  }
  __syncthreads();

  int d = tid & 31, xg = tid >> 5;
  float w[25];
  #pragma unroll
  for (int i = 0; i < 25; ++i) w[i] = Wd[d*25 + i];
  float bv = bias[d];
  #pragma unroll
  for (int rr = 0; rr < 2; ++rr) {
    int y = y0 + rr;
    float acc[8] = {};
    #pragma unroll
    for (int dy = 0; dy < 5; ++dy) {
      int yy = y + dy - 2;
      if (yy >= 0 && yy <= 63) {
        const float* rb = lds + (rr + dy)*2048 + d;
        float in[12];
        #pragma unroll
        for (int i = 0; i < 12; ++i) {
          int xx = xg*8 - 2 + i;
          in[i] = (xx < 0 || xx > 63) ? 0.f : rb[xx*32];
        }
        #pragma unroll
        for (int dx = 0; dx < 5; ++dx) {
          float ww = w[dy*5 + dx];
          #pragma unroll
          for (int j = 0; j < 8; ++j) acc[j] += ww * in[j + dx];
        }
      }
    }
    #pragma unroll
    for (int j = 0; j < 8; ++j) {
      size_t o = ((size_t)(b*4096 + y*64 + xg*8 + j))*512 + broff + e*32 + d;
      float cur = __bfloat162float(A[o]);
      A[o] = __float2bfloat16(cur + acc[j] + bv);
    }
  }
}

// ---------------- launcher ----------------
extern "C" void kernel_launch(void* const* d_in, const int* in_sizes, int n_in,
                              void* d_out, int out_size, void* d_ws, size_t ws_size,
                              hipStream_t stream)
{
  (void)in_sizes; (void)n_in; (void)out_size; (void)ws_size;
  const float* x     = (const float*)d_in[0];
  const float* Wq    = (const float*)d_in[1];
  const float* bq    = (const float*)d_in[2];
  const float* Wsr1  = (const float*)d_in[3];
  const float* bsr1  = (const float*)d_in[4];
  const float* g1    = (const float*)d_in[5];
  const float* b1    = (const float*)d_in[6];
  const float* Wsr2  = (const float*)d_in[7];
  const float* bsr2  = (const float*)d_in[8];
  const float* g2    = (const float*)d_in[9];
  const float* b2    = (const float*)d_in[10];
  const float* Wkv1  = (const float*)d_in[11];
  const float* bkv1  = (const float*)d_in[12];
  const float* Wkv2  = (const float*)d_in[13];
  const float* bkv2  = (const float*)d_in[14];
  const float* pe1   = (const float*)d_in[15];
  const float* pe2   = (const float*)d_in[16];
  const float* Wproj = (const float*)d_in[17];
  const float* bproj = (const float*)d_in[18];
  const float* Wdwc  = (const float*)d_in[19];
  const float* bdwc  = (const float*)d_in[20];
  const float* scale = (const float*)d_in[21];
  float* out = (float*)d_out;
  float* ws  = (float*)d_ws;
  dim3 blk(256);

  __hip_bfloat16* WQB    = (__hip_bfloat16*)(ws + oWQB);
  __hip_bfloat16* W1B    = (__hip_bfloat16*)(ws + oW1B);
  __hip_bfloat16* W2B    = (__hip_bfloat16*)(ws + oW2B);
  __hip_bfloat16* WKV1B  = (__hip_bfloat16*)(ws + oWKV1B);
  __hip_bfloat16* WKV2B  = (__hip_bfloat16*)(ws + oWKV2B);
  __hip_bfloat16* WPROJB = (__hip_bfloat16*)(ws + oWPROJB);
  __hip_bfloat16* X1B    = (__hip_bfloat16*)(ws + oX1B);
  __hip_bfloat16* X2B    = (__hip_bfloat16*)(ws + oX2B);
  __hip_bfloat16* AB     = (__hip_bfloat16*)(ws + oAB);
  __hip_bfloat16* QB     = (__hip_bfloat16*)(ws + oQBUF);
  __hip_bfloat16* Y1B    = (__hip_bfloat16*)(ws + oY1);
  __hip_bfloat16* Y2B    = (__hip_bfloat16*)(ws + oY2);
  __hip_bfloat16* K1P    = (__hip_bfloat16*)(ws + oK1P);
  __hip_bfloat16* K2P    = (__hip_bfloat16*)(ws + oK2P);
  __hip_bfloat16* V1G    = (__hip_bfloat16*)(ws + oV1G);
  __hip_bfloat16* V2G    = (__hip_bfloat16*)(ws + oV2G);

  // one mega pack launch
  pack_all<<<6913, blk, 0, stream>>>(Wq, Wkv1, Wkv2, Wproj, Wsr1, Wsr2, scale,
      WQB, WKV1B, WKV2B, WPROJB, W1B, W2B, ws + oINVSP);

  // q = x@Wq^T + bq -> bf16 scattered q
  gmfma<128,128,0,0,4><<<dim3(512,2), blk, 0, stream>>>(x, WQB, bq, (float*)QB, 65536, 256, 256, 256);

  // ---- branch 1 staging ----
  gmfma<64,64,1,0,3><<<dim3(64,4,4), blk, 0, stream>>>(x, W1B, bsr1, ws+oP1, 4096, 256, 1024, 4096);
  ln_gelu_sum4<<<1024, blk, 0, stream>>>(ws+oP1, bsr1, g1, b1, X1B, 4096);
  gmfma<64,64,0,1,5><<<dim3(64,8), blk, 0, stream>>>(X1B, WKV1B, bkv1, (float*)Y1B, 4096, 512, 256, 256);
  gather_kv2<1><<<256, blk, 0, stream>>>(Y1B, pe1, K1P, V1G);
  row_powernorm_bf<<<1024, blk, 0, stream>>>(K1P, ws+oINVSP, 4096);
  kmkv_part<<<512, blk, 0, stream>>>(K1P, V1G, ws+oKMP, ws+oKVP, 256);
  kmkv_red<<<512, blk, 0, stream>>>(ws+oKMP, ws+oKVP, ws+oKM1, ws+oKV1M, 1.0f/256.0f);

  // ---- branch 2 staging ----
  gmfma<64,64,2,0,0><<<dim3(256,4), blk, 0, stream>>>(x, W2B, bsr2, ws+oX2, 16384, 256, 1024, 1024);
  ln_gelu_b<<<4096, blk, 0, stream>>>(ws+oX2, g2, b2, X2B, 16384);
  gmfma<64,64,0,1,5><<<dim3(256,8), blk, 0, stream>>>(X2B, WKV2B, bkv2, (float*)Y2B, 16384, 512, 256, 256);
  gather_kv2<2><<<1024, blk, 0, stream>>>(Y2B, pe2, K2P, V2G);
  row_powernorm_bf<<<4096, blk, 0, stream>>>(K2P, ws+oINVSP, 16384);
  kmkv_part<<<512, blk, 0, stream>>>(K2P, V2G, ws+oKMP, ws+oKVP, 1024);
  kmkv_red<<<512, blk, 0, stream>>>(ws+oKMP, ws+oKVP, ws+oKM2, ws+oKV2M, 1.0f/1024.0f);

  // ---- MFMA attention v3 (bf16 q) -> AB[b,t,0:512] ----
  attn_mfma<<<1024, dim3(512), 0, stream>>>(QB, ws+oINVSP,
      ws+oKM1, ws+oKV1M, ws+oKM2, ws+oKV2M, AB);

  // ---- merged fused interp+dwconv (both branches, one launch) ----
  dwconv_f2m<<<8192, blk, 0, stream>>>(V1G, V2G, Wdwc, bdwc, AB);

  // ---- single fused projection: out = AB @ Wproj^T + bproj ----
  gmfma<128,128,0,1,0><<<dim3(512,2), blk, 0, stream>>>(AB, WPROJB, bproj, out, 65536, 256, 512, 512);
}

// Round 20
// 311.430 us; speedup vs baseline: 1.1055x; 1.0102x over previous
//
#include <hip/hip_runtime.h>
#include <hip/hip_bf16.h>
#include <cmath>

// ---------------- problem constants ----------------
constexpr int cB = 16;
constexpr int cN = 4096;
constexpr int cC = 256;

typedef __attribute__((ext_vector_type(8))) short short8;
typedef __attribute__((ext_vector_type(4))) float f32x4;

__device__ inline unsigned short bfr(float f) {
  __hip_bfloat16 h = __float2bfloat16(f);
  return *(unsigned short*)&h;
}
__device__ inline float u16tof(unsigned short u) {
  unsigned int v = ((unsigned int)u) << 16;
  return __builtin_bit_cast(float, v);
}

// ---------------- workspace layout (float units) — ~102.3 MB ----------------
constexpr size_t oWQB    = 0;                               // 256x256 bf16
constexpr size_t oW1B    = oWQB    + 32768;                 // 256x4096 bf16
constexpr size_t oW2B    = oW1B    + 524288;                // 256x1024 bf16
constexpr size_t oWKV1B  = oW2B    + 131072;
constexpr size_t oWKV2B  = oWKV1B  + 65536;
constexpr size_t oWPROJB = oWKV2B  + 65536;
constexpr size_t oINVSP  = oWPROJB + 65536;                 // 256 f32 (pad 1024)
constexpr size_t oKM1    = oINVSP  + 1024;
constexpr size_t oKV1M   = oKM1    + 4096;
constexpr size_t oKM2    = oKV1M   + 131072;
constexpr size_t oKV2M   = oKM2    + 4096;
constexpr size_t oKVP1   = oKV2M   + 131072;                // 4x131072 f32
constexpr size_t oKMP1   = oKVP1   + 524288;                // 4x4096 f32
constexpr size_t oKVP2   = oKMP1   + 16384;                 // 4x131072 f32
constexpr size_t oKMP2   = oKVP2   + 524288;                // 4x4096 f32
constexpr size_t oQBUF   = oKMP2   + 16384;                 // q bf16 (8388608 fu)
constexpr size_t oV1G    = oQBUF   + 8388608;               // bf16 16x256x256  (524288 fu)
constexpr size_t oV2G    = oV1G    + 524288;                // bf16 16x1024x256 (2097152 fu)
constexpr size_t oX1B    = oV2G    + 2097152;               // bf16 4096x256 (262144 fu), dedicated
constexpr size_t oY1     = oX1B    + 262144;                // bf16 4096x512 (1048576 fu), dedicated
constexpr size_t oK1P    = oY1     + 1048576;               // bf16 4096x256 (524288 fu), dedicated
constexpr size_t oU      = oK1P    + 524288;                // union, 10,485,760 fu
// union (time-multiplexed):
constexpr size_t oP1     = oU;                              // 4x(4096x256) f32
constexpr size_t oX2     = oU;                              // f32 16384x256 (after P1 dead)
constexpr size_t oY2     = oU + 4194304;                    // bf16 16384x512 (4194304 fu)
constexpr size_t oX2B    = oU + 8388608;                    // bf16 16384x256 (2097152 fu)
constexpr size_t oK2P    = oU;                              // bf16 16384x256 (2097152 fu), after X2 dead
constexpr size_t oAB     = oU;                              // bf16 16x4096x512 (8388608 fu), after K2P/Y2B dead

// ---------------- one mega weight-pack kernel ----------------
__global__ __launch_bounds__(256) void pack_all(
    const float* __restrict__ Wq,   const float* __restrict__ Wkv1,
    const float* __restrict__ Wkv2, const float* __restrict__ Wproj,
    const float* __restrict__ Wsr1, const float* __restrict__ Wsr2,
    const float* __restrict__ scale,
    __hip_bfloat16* WQB, __hip_bfloat16* WKV1B, __hip_bfloat16* WKV2B,
    __hip_bfloat16* WPROJB, __hip_bfloat16* W1B, __hip_bfloat16* W2B,
    float* inv_sp)
{
  int bid = blockIdx.x, tid = threadIdx.x;
  if (bid < 256) {
    int i = bid*256 + tid; WQB[i] = __float2bfloat16(Wq[i]);
  } else if (bid < 768) {
    int i = (bid-256)*256 + tid; WKV1B[i] = __float2bfloat16(Wkv1[i]);
  } else if (bid < 1280) {
    int i = (bid-768)*256 + tid; WKV2B[i] = __float2bfloat16(Wkv2[i]);
  } else if (bid < 1792) {
    int i = (bid-1280)*256 + tid; WPROJB[i] = __float2bfloat16(Wproj[i]);
  } else if (bid < 5888) {
    int i = (bid-1792)*256 + tid;          // ((co*16+p)*256+ci)
    int ci = i & 255, rest = i >> 8;
    int p = rest & 15, co = rest >> 4;
    W1B[i] = __float2bfloat16(Wsr1[((size_t)co*256 + ci)*16 + p]);
  } else if (bid < 6912) {
    int i = (bid-5888)*256 + tid;          // ((co*4+p)*256+ci)
    int ci = i & 255, rest = i >> 8;
    int p = rest & 3, co = rest >> 2;
    W2B[i] = __float2bfloat16(Wsr2[((size_t)co*256 + ci)*4 + p]);
  } else {
    float v = scale[tid];
    float sp = (v > 20.f) ? v : log1pf(expf(v));
    inv_sp[tid] = 1.f/sp;
  }
}

// ---------------- MFMA bf16 GEMM ----------------
// AMODE: 0 row-major A; 1/2 conv patch gather. ADT: 0 f32 A, 1 bf16 A.
// EPI: 0 C=acc+bias f32; 1 q-scatter f32; 2 C+=acc; 3 partial; 4 q-scatter bf16; 5 C=acc+bias bf16
template<int TM, int TN, int AMODE, int ADT, int EPI>
__global__ __launch_bounds__(256) void gmfma(
    const void* __restrict__ Asrc, const __hip_bfloat16* __restrict__ Bp,
    const float* __restrict__ bias, float* __restrict__ Cout,
    int M, int N, int K, int ldb)
{
  constexpr int APASS = TM/32, BPASS = TN/32;
  constexpr int WGM = (TM==128) ? 2 : ((TN==64) ? 2 : 1);
  constexpr int WGN = 4/WGM;
  constexpr int WM = TM/WGM, WN = TN/WGN;
  constexpr int FM = WM/16, FN = WN/16;
  __shared__ char smem[(TM+TN)*128];
  char* As = smem;
  char* Bs = smem + TM*128;
  const int tid  = threadIdx.x;
  const int row0 = blockIdx.x * TM;
  const int col0 = blockIdx.y * TN;
  const int kbase = blockIdx.z * K;
  const int kq = tid & 7, rl = tid >> 3;
  const int w = tid >> 6, lane = tid & 63;
  const int wr = (WGM==2) ? (w>>1) : 0;
  const int wc = (WGM==2) ? (w&1)  : w;

  f32x4 acc[FM][FN] = {};
  short8 aS[APASS], bS[BPASS];

  auto loadA = [&](int k0) {
    int ka = kbase + k0;
    #pragma unroll
    for (int p = 0; p < APASS; ++p) {
      int r = row0 + rl + p*32;
      const char* ap;
      if (AMODE == 0) {
        if (ADT == 0) ap = (const char*)((const float*)Asrc + (size_t)r*K + k0 + kq*8);
        else          ap = (const char*)((const __hip_bfloat16*)Asrc + (size_t)r*K + k0 + kq*8);
      } else if (AMODE == 1) {
        int b = r >> 8, mm = r & 255;
        int my = mm >> 4, mx = mm & 15;
        int ch = ka >> 8, ky = ch >> 2, kx = ch & 3;
        int tok = (4*my + ky)*64 + 4*mx + kx;
        ap = (const char*)((const float*)Asrc + ((size_t)(b*4096 + tok))*256 + (ka & 255) + kq*8);
      } else {
        int b = r >> 10, mm = r & 1023;
        int my = mm >> 5, mx = mm & 31;
        int ch = ka >> 8, ky = ch >> 1, kx = ch & 1;
        int tok = (2*my + ky)*64 + 2*mx + kx;
        ap = (const char*)((const float*)Asrc + ((size_t)(b*4096 + tok))*256 + (ka & 255) + kq*8);
      }
      if (ADT == 0) {
        float4 v0 = *(const float4*)ap;
        float4 v1 = *(const float4*)(ap + 16);
        short8 s;
        s[0] = (short)bfr(v0.x); s[1] = (short)bfr(v0.y);
        s[2] = (short)bfr(v0.z); s[3] = (short)bfr(v0.w);
        s[4] = (short)bfr(v1.x); s[5] = (short)bfr(v1.y);
        s[6] = (short)bfr(v1.z); s[7] = (short)bfr(v1.w);
        aS[p] = s;
      } else {
        aS[p] = *(const short8*)ap;
      }
    }
  };
  auto loadB = [&](int k0) {
    #pragma unroll
    for (int p = 0; p < BPASS; ++p) {
      int n = col0 + rl + p*32;
      bS[p] = *(const short8*)(Bp + (size_t)n*ldb + kbase + k0 + kq*8);
    }
  };

  loadA(0); loadB(0);
  for (int k0 = 0; k0 < K; k0 += 64) {
    #pragma unroll
    for (int p = 0; p < APASS; ++p) {
      int r = rl + p*32;
      *(short8*)(As + r*128 + ((kq*16) ^ ((r&7)<<4))) = aS[p];
    }
    #pragma unroll
    for (int p = 0; p < BPASS; ++p) {
      int n = rl + p*32;
      *(short8*)(Bs + n*128 + ((kq*16) ^ ((n&7)<<4))) = bS[p];
    }
    __syncthreads();
    if (k0 + 64 < K) { loadA(k0 + 64); loadB(k0 + 64); }
    #pragma unroll
    for (int ks = 0; ks < 2; ++ks) {
      short8 af[FM], bfv[FN];
      #pragma unroll
      for (int i = 0; i < FM; ++i) {
        int r = wr*WM + i*16 + (lane & 15);
        af[i] = *(const short8*)(As + r*128 + ((ks*64 + (lane>>4)*16) ^ ((r&7)<<4)));
      }
      #pragma unroll
      for (int j = 0; j < FN; ++j) {
        int n = wc*WN + j*16 + (lane & 15);
        bfv[j] = *(const short8*)(Bs + n*128 + ((ks*64 + (lane>>4)*16) ^ ((n&7)<<4)));
      }
      #pragma unroll
      for (int i = 0; i < FM; ++i)
        #pragma unroll
        for (int j = 0; j < FN; ++j)
          acc[i][j] = __builtin_amdgcn_mfma_f32_16x16x32_bf16(af[i], bfv[j], acc[i][j], 0, 0, 0);
    }
    __syncthreads();
  }

  #pragma unroll
  for (int i = 0; i < FM; ++i) {
    #pragma unroll
    for (int j = 0; j < FN; ++j) {
      int cc = col0 + wc*WN + j*16 + (lane & 15);
      float bval = (EPI == 2 || EPI == 3) ? 0.f : bias[cc];
      #pragma unroll
      for (int rg = 0; rg < 4; ++rg) {
        int rr = row0 + wr*WM + i*16 + (lane>>4)*4 + rg;
        float v = acc[i][j][rg] + bval;
        if (EPI == 0) {
          Cout[(size_t)rr*N + cc] = v;
        } else if (EPI == 1) {
          int b = rr >> 12, n = rr & 4095;
          int h = cc >> 5, d = cc & 31;
          Cout[((size_t)(b*4096 + h*512 + (n >> 3)))*256 + (n & 7)*32 + d] = v;
        } else if (EPI == 2) {
          Cout[(size_t)rr*N + cc] += v;
        } else if (EPI == 3) {
          Cout[(size_t)blockIdx.z*((size_t)M*N) + (size_t)rr*N + cc] = v;
        } else if (EPI == 4) {
          int b = rr >> 12, n = rr & 4095;
          int h = cc >> 5, d = cc & 31;
          ((__hip_bfloat16*)Cout)[((size_t)(b*4096 + h*512 + (n >> 3)))*256 + (n & 7)*32 + d] =
              __float2bfloat16(v);
        } else {
          ((__hip_bfloat16*)Cout)[(size_t)rr*N + cc] = __float2bfloat16(v);
        }
      }
    }
  }
}

// ---------------- merged bf16 row powernorm (both branches) ----------------
__global__ __launch_bounds__(256) void row_powernorm_m(__hip_bfloat16* __restrict__ k1,
    __hip_bfloat16* __restrict__ k2, const float* __restrict__ inv_sp)
{
  int row = blockIdx.x*4 + (threadIdx.x >> 6);   // 0..20479
  int lane = threadIdx.x & 63;
  __hip_bfloat16* p = (row < 4096) ? (k1 + (size_t)row*256 + lane*4)
                                   : (k2 + (size_t)(row-4096)*256 + lane*4);
  ushort4 u = *(ushort4*)p;
  const float4 is = *(const float4*)(inv_sp + lane*4);
  float r0 = (fmaxf(u16tof(u.x),0.f)+1e-6f)*is.x;
  float r1 = (fmaxf(u16tof(u.y),0.f)+1e-6f)*is.y;
  float r2 = (fmaxf(u16tof(u.z),0.f)+1e-6f)*is.z;
  float r3 = (fmaxf(u16tof(u.w),0.f)+1e-6f)*is.w;
  float s2 = r0*r0+r1*r1+r2*r2+r3*r3;
  #pragma unroll
  for (int o = 1; o < 64; o <<= 1) s2 += __shfl_xor(s2, o, 64);
  float c0 = r0*r0*r0, c1 = r1*r1*r1, c2 = r2*r2*r2, c3 = r3*r3*r3;
  float s6 = c0*c0+c1*c1+c2*c2+c3*c3;
  #pragma unroll
  for (int o = 1; o < 64; o <<= 1) s6 += __shfl_xor(s6, o, 64);
  float f = sqrtf(s2/s6);
  ushort4 w;
  w.x = bfr(c0*f); w.y = bfr(c1*f); w.z = bfr(c2*f); w.w = bfr(c3*f);
  *(ushort4*)p = w;
}

// ---------------- sum 4 split-K partials + bias, LayerNorm + GELU -> bf16 ----------------
__global__ __launch_bounds__(256) void ln_gelu_sum4(const float* __restrict__ P,
    const float* __restrict__ bias, const float* __restrict__ g, const float* __restrict__ bb,
    __hip_bfloat16* __restrict__ outb, int rows)
{
  const size_t PS = (size_t)rows*256;
  int row = blockIdx.x*4 + (threadIdx.x >> 6);
  if (row >= rows) return;
  int lane = threadIdx.x & 63;
  const float* p = P + (size_t)row*256 + lane*4;
  float4 v0 = *(const float4*)p;
  float4 v1 = *(const float4*)(p + PS);
  float4 v2 = *(const float4*)(p + 2*PS);
  float4 v3 = *(const float4*)(p + 3*PS);
  float4 bsv = *(const float4*)(bias + lane*4);
  float4 v;
  v.x = v0.x+v1.x+v2.x+v3.x+bsv.x;
  v.y = v0.y+v1.y+v2.y+v3.y+bsv.y;
  v.z = v0.z+v1.z+v2.z+v3.z+bsv.z;
  v.w = v0.w+v1.w+v2.w+v3.w+bsv.w;
  float s = v.x+v.y+v.z+v.w;
  #pragma unroll
  for (int o = 1; o < 64; o <<= 1) s += __shfl_xor(s, o, 64);
  float mu = s*(1.f/256.f);
  float d0 = v.x-mu, d1 = v.y-mu, d2 = v.z-mu, d3 = v.w-mu;
  float q = d0*d0+d1*d1+d2*d2+d3*d3;
  #pragma unroll
  for (int o = 1; o < 64; o <<= 1) q += __shfl_xor(q, o, 64);
  float rstd = rsqrtf(q*(1.f/256.f) + 1e-5f);
  float4 gv = *(const float4*)(g + lane*4);
  float4 bv = *(const float4*)(bb + lane*4);
  float y0 = d0*rstd*gv.x + bv.x;
  float y1 = d1*rstd*gv.y + bv.y;
  float y2 = d2*rstd*gv.z + bv.z;
  float y3 = d3*rstd*gv.w + bv.w;
  const float k = 0.70710678118654752f;
  ushort4 u;
  u.x = bfr(0.5f*y0*(1.f+erff(y0*k)));
  u.y = bfr(0.5f*y1*(1.f+erff(y1*k)));
  u.z = bfr(0.5f*y2*(1.f+erff(y2*k)));
  u.w = bfr(0.5f*y3*(1.f+erff(y3*k)));
  *(ushort4*)(outb + (size_t)row*256 + lane*4) = u;
}

// ---------------- LayerNorm + exact GELU: f32 in, bf16 out ----------------
__global__ __launch_bounds__(256) void ln_gelu_b(const float* __restrict__ x,
    const float* __restrict__ g, const float* __restrict__ bb,
    __hip_bfloat16* __restrict__ outb, int rows)
{
  int row = blockIdx.x*4 + (threadIdx.x >> 6);
  if (row >= rows) return;
  int lane = threadIdx.x & 63;
  const float* p = x + (size_t)row*256 + lane*4;
  float4 v = *(const float4*)p;
  float s = v.x+v.y+v.z+v.w;
  #pragma unroll
  for (int o = 1; o < 64; o <<= 1) s += __shfl_xor(s, o, 64);
  float mu = s*(1.f/256.f);
  float d0 = v.x-mu, d1 = v.y-mu, d2 = v.z-mu, d3 = v.w-mu;
  float q = d0*d0+d1*d1+d2*d2+d3*d3;
  #pragma unroll
  for (int o = 1; o < 64; o <<= 1) q += __shfl_xor(q, o, 64);
  float rstd = rsqrtf(q*(1.f/256.f) + 1e-5f);
  float4 gv = *(const float4*)(g + lane*4);
  float4 bv = *(const float4*)(bb + lane*4);
  float y0 = d0*rstd*gv.x + bv.x;
  float y1 = d1*rstd*gv.y + bv.y;
  float y2 = d2*rstd*gv.z + bv.z;
  float y3 = d3*rstd*gv.w + bv.w;
  const float k = 0.70710678118654752f;
  ushort4 u;
  u.x = bfr(0.5f*y0*(1.f+erff(y0*k)));
  u.y = bfr(0.5f*y1*(1.f+erff(y1*k)));
  u.z = bfr(0.5f*y2*(1.f+erff(y2*k)));
  u.w = bfr(0.5f*y3*(1.f+erff(y3*k)));
  *(ushort4*)(outb + (size_t)row*256 + lane*4) = u;
}

// ---------------- merged fused k+v gather (both branches, one launch) ----------------
__global__ __launch_bounds__(256) void gather_m(const __hip_bfloat16* __restrict__ y1,
    const __hip_bfloat16* __restrict__ y2,
    const float* __restrict__ pe1, const float* __restrict__ pe2,
    __hip_bfloat16* __restrict__ K1, __hip_bfloat16* __restrict__ V1,
    __hip_bfloat16* __restrict__ K2, __hip_bfloat16* __restrict__ V2)
{
  __shared__ float tk[64][65];
  __shared__ float tv[64][65];
  int bidx = blockIdx.x;                  // [0,256) br1, [256,1280) br2
  bool br2 = bidx >= 256;
  int bid = br2 ? (bidx - 256) : bidx;
  const __hip_bfloat16* y = br2 ? y2 : y1;
  const float* pe = br2 ? pe2 : pe1;
  __hip_bfloat16* Ko = br2 ? K2 : K1;
  __hip_bfloat16* Vo = br2 ? V2 : V1;
  const int NKV = br2 ? 1024 : 256;

  int cb = bid & 3;
  int nb = (bid >> 2) % (NKV/64);
  int b  = (bid >> 2) / (NKV/64);
  int n0 = nb*64, c0 = cb*64;
  int tid = threadIdx.x;
  #pragma unroll
  for (int pass = 0; pass < 16; ++pass) {
    int c_l = (tid >> 6)*16 + pass;
    int c = c0 + c_l;
    if (!br2) {
      int n_l = tid & 63;
      size_t base = ((size_t)(b*256 + c))*512 + 2*(n0 + n_l);
      tk[c_l][n_l] = __bfloat162float(y[base]);
      tv[c_l][n_l] = __bfloat162float(y[base + 1]);
    } else {
      int u = tid & 31, pp = (tid >> 5) & 1;
      int n_l = 2*u + pp;
      size_t rk = ((size_t)(b*1024 + pp*512 + c))*512 + (size_t)((n0 >> 1) + u);
      tk[c_l][n_l] = __bfloat162float(y[rk]);
      tv[c_l][n_l] = __bfloat162float(y[rk + (size_t)256*512]);
    }
  }
  __syncthreads();
  #pragma unroll
  for (int pass = 0; pass < 16; ++pass) {
    int n_l = (tid >> 6)*16 + pass;
    int c_l = tid & 63;
    int n = n0 + n_l, c = c0 + c_l;
    size_t o = ((size_t)(b*NKV + n))*256 + c;
    Ko[o] = __float2bfloat16(tk[c_l][n_l] + pe[n*256 + c]);
    Vo[o] = __float2bfloat16(tv[c_l][n_l]);
  }
}

// ---------------- merged kmkv split-N partials (both branches) ----------------
__global__ __launch_bounds__(256) void kmkv_part_m(const __hip_bfloat16* __restrict__ k1,
    const __hip_bfloat16* __restrict__ v1, const __hip_bfloat16* __restrict__ k2,
    const __hip_bfloat16* __restrict__ v2,
    float* __restrict__ kmp1, float* __restrict__ kvp1,
    float* __restrict__ kmp2, float* __restrict__ kvp2)
{
  int g = blockIdx.x;                     // [0,512) br1, [512,1024) br2
  bool br2 = g >= 512;
  if (br2) g -= 512;
  const __hip_bfloat16* kp = br2 ? k2 : k1;
  const __hip_bfloat16* vg = br2 ? v2 : v1;
  float* kmp = br2 ? kmp2 : kmp1;
  float* kvp = br2 ? kvp2 : kvp1;
  const int nkv = br2 ? 1024 : 256;

  int ch = g & 3, bh = g >> 2;
  int b = bh >> 3, h = bh & 7;
  int nchunk = nkv >> 2;
  int tid = threadIdx.x;
  __shared__ float ks[64][32];
  __shared__ float vs[64][32];
  int d  = tid >> 3;
  int e0 = (tid & 7)*4;
  float acc[4] = {0.f,0.f,0.f,0.f};
  float kmacc = 0.f;
  for (int n0 = ch*nchunk; n0 < (ch+1)*nchunk; n0 += 64) {
    #pragma unroll
    for (int i = 0; i < 2; ++i) {
      int f = tid + i*256;
      int nn = f >> 3, q4 = (f & 7)*4;
      size_t base = ((size_t)(b*nkv + n0 + nn))*256 + h*32 + q4;
      ushort4 ku = *(const ushort4*)(kp + base);
      ushort4 vu = *(const ushort4*)(vg + base);
      float4 kf, vf;
      kf.x = u16tof(ku.x); kf.y = u16tof(ku.y); kf.z = u16tof(ku.z); kf.w = u16tof(ku.w);
      vf.x = u16tof(vu.x); vf.y = u16tof(vu.y); vf.z = u16tof(vu.z); vf.w = u16tof(vu.w);
      *(float4*)&ks[nn][q4] = kf;
      *(float4*)&vs[nn][q4] = vf;
    }
    __syncthreads();
    #pragma unroll 8
    for (int nn = 0; nn < 64; ++nn) {
      float kd = ks[nn][d];
      kmacc += kd;
      #pragma unroll
      for (int j = 0; j < 4; ++j) acc[j] += kd * vs[nn][e0+j];
    }
    __syncthreads();
  }
  const float s2c = 1.0f/4096.0f;
  #pragma unroll
  for (int j = 0; j < 4; ++j)
    kvp[(size_t)ch*131072 + ((size_t)bh*32 + e0 + j)*32 + d] = acc[j]*s2c;
  if ((tid & 7) == 0) kmp[ch*4096 + bh*32 + d] = kmacc;
}

// ---------------- merged kmkv reduce (both branches) ----------------
__global__ __launch_bounds__(256) void kmkv_red_m(const float* __restrict__ kmp1,
    const float* __restrict__ kvp1, const float* __restrict__ kmp2,
    const float* __restrict__ kvp2,
    float* __restrict__ km1, float* __restrict__ kvm1,
    float* __restrict__ km2, float* __restrict__ kvm2)
{
  int idx = blockIdx.x*256 + threadIdx.x;   // 262144
  bool br2 = idx >= 131072;
  if (br2) idx -= 131072;
  const float* kmp = br2 ? kmp2 : kmp1;
  const float* kvp = br2 ? kvp2 : kvp1;
  float* km = br2 ? km2 : km1;
  float* kvm = br2 ? kvm2 : kvm1;
  float inv_nkv = br2 ? (1.0f/1024.0f) : (1.0f/256.0f);
  kvm[idx] = kvp[idx] + kvp[131072 + idx] + kvp[262144 + idx] + kvp[393216 + idx];
  if (idx < 4096)
    km[idx] = (kmp[idx] + kmp[4096 + idx] + kmp[8192 + idx] + kmp[12288 + idx]) * inv_nkv;
}

// ---------------- MFMA attention v3 (proven) ----------------
__global__ __launch_bounds__(512) void attn_mfma(const __hip_bfloat16* __restrict__ q,
    const float* __restrict__ inv_sp,
    const float* __restrict__ km1, const float* __restrict__ kv1,
    const float* __restrict__ km2, const float* __restrict__ kv2,
    __hip_bfloat16* __restrict__ A)
{
  __shared__ __align__(16) char qs[64*512];
  __shared__ __align__(16) char kvs[32*512];
  __shared__ float zsf[2*64*8];   // [br][t_l][h]
  const int bid = blockIdx.x;
  const int b = bid >> 6, t0 = (bid & 63)*64;
  const int tid = threadIdx.x;

  {
    const float* src = kv1 + (size_t)b*8192;
    for (int i = tid; i < 8192; i += 512) {
      int h = i >> 10, e = (i >> 5) & 31, d = i & 31;
      *(unsigned short*)(kvs + e*512 + ((h*64 + d*2) ^ ((e&7)<<4))) = bfr(src[i]);
    }
  }

  {
    const int h = tid & 7;
    const int t_l = tid >> 3;
    const float* km1p = km1 + b*256 + h*32;
    const float* km2p = km2 + b*256 + h*32;
    const __hip_bfloat16* qp = q + ((size_t)(b*4096 + t0 + t_l))*256 + h*32;
    float cf[32];
    float s2 = 0.f, s6 = 0.f;
    #pragma unroll
    for (int j = 0; j < 4; ++j) {
      short8 qv = *(const short8*)(qp + j*8);
      float4 is0 = *(const float4*)(inv_sp + h*32 + j*8);
      float4 is1 = *(const float4*)(inv_sp + h*32 + j*8 + 4);
      float isv[8] = {is0.x, is0.y, is0.z, is0.w, is1.x, is1.y, is1.z, is1.w};
      #pragma unroll
      for (int k = 0; k < 8; ++k) {
        float val = u16tof((unsigned short)qv[k]);
        float r = (fmaxf(val, 0.f) + 1e-6f) * isv[k];
        s2 += r*r;
        float c = r*r*r;
        s6 += c*c;
        cf[j*8 + k] = c;
      }
    }
    #pragma unroll
    for (int o = 1; o < 8; o <<= 1) {
      s2 += __shfl_xor(s2, o, 64);
      s6 += __shfl_xor(s6, o, 64);
    }
    float f = sqrtf(s2/s6);
    float d1 = 0.f, d2 = 0.f;
    #pragma unroll
    for (int j = 0; j < 8; ++j) {
      float4 k1 = *(const float4*)(km1p + j*4);
      float4 k2 = *(const float4*)(km2p + j*4);
      float q0 = cf[4*j+0]*f, q1 = cf[4*j+1]*f, q2 = cf[4*j+2]*f, q3 = cf[4*j+3]*f;
      cf[4*j+0] = q0; cf[4*j+1] = q1; cf[4*j+2] = q2; cf[4*j+3] = q3;
      d1 += q0*k1.x + q1*k1.y + q2*k1.z + q3*k1.w;
      d2 += q0*k2.x + q1*k2.y + q2*k2.z + q3*k2.w;
    }
    zsf[0*512 + t_l*8 + h] = 1.0f/(d1 + 1e-6f);
    zsf[1*512 + t_l*8 + h] = 1.0f/(d2 + 1e-6f);
    #pragma unroll
    for (int j = 0; j < 4; ++j) {
      short8 s;
      #pragma unroll
      for (int k = 0; k < 8; ++k) s[k] = (short)bfr(cf[j*8+k]);
      *(short8*)(qs + t_l*512 + ((h*64 + j*16) ^ ((t_l&7)<<4))) = s;
    }
  }
  __syncthreads();

  const int h = tid >> 6, l = tid & 63;
  const int lr = l & 15, lk = l >> 4;
  #pragma unroll
  for (int br = 0; br < 2; ++br) {
    if (br == 1) {
      __syncthreads();
      const float* src = kv2 + (size_t)b*8192;
      for (int i = tid; i < 8192; i += 512) {
        int hh = i >> 10, e = (i >> 5) & 31, d = i & 31;
        *(unsigned short*)(kvs + e*512 + ((hh*64 + d*2) ^ ((e&7)<<4))) = bfr(src[i]);
      }
      __syncthreads();
    }
    #pragma unroll
    for (int tt = 0; tt < 4; ++tt) {
      int tr = tt*16 + lr;
      short8 af = *(const short8*)(qs + tr*512 + ((h*64 + lk*16) ^ ((tr&7)<<4)));
      #pragma unroll
      for (int eb = 0; eb < 2; ++eb) {
        int e = eb*16 + lr;
        short8 bf = *(const short8*)(kvs + e*512 + ((h*64 + lk*16) ^ ((e&7)<<4)));
        f32x4 acc = {0.f, 0.f, 0.f, 0.f};
        acc = __builtin_amdgcn_mfma_f32_16x16x32_bf16(af, bf, acc, 0, 0, 0);
        #pragma unroll
        for (int rg = 0; rg < 4; ++rg) {
          int row = lk*4 + rg;
          float z = zsf[br*512 + (tt*16 + row)*8 + h];
          A[((size_t)(b*4096 + t0 + tt*16 + row))*512 + br*256 + h*32 + e] =
              __float2bfloat16(acc[rg]*z);
        }
      }
    }
  }
}

// ---------------- merged fused interp + 5x5 dwconv (both branches, one launch) ----------------
__global__ __launch_bounds__(256) void dwconv_f2m(const __hip_bfloat16* __restrict__ v1,
    const __hip_bfloat16* __restrict__ v2,
    const float* __restrict__ Wd, const float* __restrict__ bias,
    __hip_bfloat16* __restrict__ A)
{
  __shared__ float lds[6*2048];
  int bidx = blockIdx.x;                  // 8192 blocks: [0,4096) br1, [4096,8192) br2
  bool br2 = bidx >= 4096;
  int wg = br2 ? (bidx - 4096) : bidx;
  const __hip_bfloat16* vg = br2 ? v2 : v1;
  const int broff = br2 ? 256 : 0;
  const int L    = br2 ? 1024 : 256;
  const int RPSH = br2 ? 7 : 5;
  const int NM   = (L >> 3) - 1;
  const float sc = br2 ? 0.25f : 0.0625f;
  const float lmax = (float)(L - 1);

  int wid = (wg & 7)*512 + (wg >> 3);     // XCD-chunked per branch half
  int yp = wid & 31;
  int be = wid >> 5;
  int y0 = yp*2;
  int b = be >> 3, e = be & 7;
  int tid = threadIdx.x;

  {
    int d0 = (tid & 7)*4;
    #pragma unroll
    for (int c = 0; c < 2; ++c) {
      int xs = c*32 + (tid >> 3);
      int xg = xs >> 3, xl = xs & 7;
      #pragma unroll
      for (int r = 0; r < 6; ++r) {
        int yy = y0 + r - 2;
        if (yy < 0 || yy > 63) continue;
        int t = e*512 + yy*8 + xg;
        float cpos = ((float)t + 0.5f) * sc - 0.5f;
        cpos = fminf(fmaxf(cpos, 0.0f), lmax);
        int i0 = (int)cpos;
        float w = cpos - (float)i0;
        int i1 = (i0 + 1 < L) ? i0 + 1 : L - 1;
        int n0 = ((i0 & NM) << 3) + xl, ch0 = ((i0 >> RPSH) << 5) + d0;
        int n1 = ((i1 & NM) << 3) + xl, ch1 = ((i1 >> RPSH) << 5) + d0;
        ushort4 au = *(const ushort4*)(vg + ((size_t)(b*L + n0))*256 + ch0);
        ushort4 bu = *(const ushort4*)(vg + ((size_t)(b*L + n1))*256 + ch1);
        float4 o;
        float ax = u16tof(au.x), ay = u16tof(au.y), az = u16tof(au.z), aw = u16tof(au.w);
        o.x = ax + (u16tof(bu.x) - ax)*w;
        o.y = ay + (u16tof(bu.y) - ay)*w;
        o.z = az + (u16tof(bu.z) - az)*w;
        o.w = aw + (u16tof(bu.w) - aw)*w;
        *(float4*)(lds + r*2048 + xs*32 + d0) = o;
      }
    }
  }
  __syncthreads();

  int d = tid & 31, xg = tid >> 5;
  float w[25];
  #pragma unroll
  for (int i = 0; i < 25; ++i) w[i] = Wd[d*25 + i];
  float bv = bias[d];
  #pragma unroll
  for (int rr = 0; rr < 2; ++rr) {
    int y = y0 + rr;
    float acc[8] = {};
    #pragma unroll
    for (int dy = 0; dy < 5; ++dy) {
      int yy = y + dy - 2;
      if (yy >= 0 && yy <= 63) {
        const float* rb = lds + (rr + dy)*2048 + d;
        float in[12];
        #pragma unroll
        for (int i = 0; i < 12; ++i) {
          int xx = xg*8 - 2 + i;
          in[i] = (xx < 0 || xx > 63) ? 0.f : rb[xx*32];
        }
        #pragma unroll
        for (int dx = 0; dx < 5; ++dx) {
          float ww = w[dy*5 + dx];
          #pragma unroll
          for (int j = 0; j < 8; ++j) acc[j] += ww * in[j + dx];
        }
      }
    }
    #pragma unroll
    for (int j = 0; j < 8; ++j) {
      size_t o = ((size_t)(b*4096 + y*64 + xg*8 + j))*512 + broff + e*32 + d;
      float cur = __bfloat162float(A[o]);
      A[o] = __float2bfloat16(cur + acc[j] + bv);
    }
  }
}

// ---------------- launcher ----------------
extern "C" void kernel_launch(void* const* d_in, const int* in_sizes, int n_in,
                              void* d_out, int out_size, void* d_ws, size_t ws_size,
                              hipStream_t stream)
{
  (void)in_sizes; (void)n_in; (void)out_size; (void)ws_size;
  const float* x     = (const float*)d_in[0];
  const float* Wq    = (const float*)d_in[1];
  const float* bq    = (const float*)d_in[2];
  const float* Wsr1  = (const float*)d_in[3];
  const float* bsr1  = (const float*)d_in[4];
  const float* g1    = (const float*)d_in[5];
  const float* b1    = (const float*)d_in[6];
  const float* Wsr2  = (const float*)d_in[7];
  const float* bsr2  = (const float*)d_in[8];
  const float* g2    = (const float*)d_in[9];
  const float* b2    = (const float*)d_in[10];
  const float* Wkv1  = (const float*)d_in[11];
  const float* bkv1  = (const float*)d_in[12];
  const float* Wkv2  = (const float*)d_in[13];
  const float* bkv2  = (const float*)d_in[14];
  const float* pe1   = (const float*)d_in[15];
  const float* pe2   = (const float*)d_in[16];
  const float* Wproj = (const float*)d_in[17];
  const float* bproj = (const float*)d_in[18];
  const float* Wdwc  = (const float*)d_in[19];
  const float* bdwc  = (const float*)d_in[20];
  const float* scale = (const float*)d_in[21];
  float* out = (float*)d_out;
  float* ws  = (float*)d_ws;
  dim3 blk(256);

  __hip_bfloat16* WQB    = (__hip_bfloat16*)(ws + oWQB);
  __hip_bfloat16* W1B    = (__hip_bfloat16*)(ws + oW1B);
  __hip_bfloat16* W2B    = (__hip_bfloat16*)(ws + oW2B);
  __hip_bfloat16* WKV1B  = (__hip_bfloat16*)(ws + oWKV1B);
  __hip_bfloat16* WKV2B  = (__hip_bfloat16*)(ws + oWKV2B);
  __hip_bfloat16* WPROJB = (__hip_bfloat16*)(ws + oWPROJB);
  __hip_bfloat16* X1B    = (__hip_bfloat16*)(ws + oX1B);
  __hip_bfloat16* X2B    = (__hip_bfloat16*)(ws + oX2B);
  __hip_bfloat16* AB     = (__hip_bfloat16*)(ws + oAB);
  __hip_bfloat16* QB     = (__hip_bfloat16*)(ws + oQBUF);
  __hip_bfloat16* Y1B    = (__hip_bfloat16*)(ws + oY1);
  __hip_bfloat16* Y2B    = (__hip_bfloat16*)(ws + oY2);
  __hip_bfloat16* K1P    = (__hip_bfloat16*)(ws + oK1P);
  __hip_bfloat16* K2P    = (__hip_bfloat16*)(ws + oK2P);
  __hip_bfloat16* V1G    = (__hip_bfloat16*)(ws + oV1G);
  __hip_bfloat16* V2G    = (__hip_bfloat16*)(ws + oV2G);

  // one mega pack launch
  pack_all<<<6913, blk, 0, stream>>>(Wq, Wkv1, Wkv2, Wproj, Wsr1, Wsr2, scale,
      WQB, WKV1B, WKV2B, WPROJB, W1B, W2B, ws + oINVSP);

  // q = x@Wq^T + bq -> bf16 scattered q
  gmfma<128,128,0,0,4><<<dim3(512,2), blk, 0, stream>>>(x, WQB, bq, (float*)QB, 65536, 256, 256, 256);

  // ---- conv chains (branch 1 then branch 2; Y1B survives in dedicated storage) ----
  gmfma<64,64,1,0,3><<<dim3(64,4,4), blk, 0, stream>>>(x, W1B, bsr1, ws+oP1, 4096, 256, 1024, 4096);
  ln_gelu_sum4<<<1024, blk, 0, stream>>>(ws+oP1, bsr1, g1, b1, X1B, 4096);
  gmfma<64,64,0,1,5><<<dim3(64,8), blk, 0, stream>>>(X1B, WKV1B, bkv1, (float*)Y1B, 4096, 512, 256, 256);
  gmfma<64,64,2,0,0><<<dim3(256,4), blk, 0, stream>>>(x, W2B, bsr2, ws+oX2, 16384, 256, 1024, 1024);
  ln_gelu_b<<<4096, blk, 0, stream>>>(ws+oX2, g2, b2, X2B, 16384);
  gmfma<64,64,0,1,5><<<dim3(256,8), blk, 0, stream>>>(X2B, WKV2B, bkv2, (float*)Y2B, 16384, 512, 256, 256);

  // ---- merged staging tail (both branches per launch) ----
  gather_m<<<1280, blk, 0, stream>>>(Y1B, Y2B, pe1, pe2, K1P, V1G, K2P, V2G);
  row_powernorm_m<<<5120, blk, 0, stream>>>(K1P, K2P, ws+oINVSP);
  kmkv_part_m<<<1024, blk, 0, stream>>>(K1P, V1G, K2P, V2G,
      ws+oKMP1, ws+oKVP1, ws+oKMP2, ws+oKVP2);
  kmkv_red_m<<<1024, blk, 0, stream>>>(ws+oKMP1, ws+oKVP1, ws+oKMP2, ws+oKVP2,
      ws+oKM1, ws+oKV1M, ws+oKM2, ws+oKV2M);

  // ---- MFMA attention v3 (bf16 q) -> AB[b,t,0:512] ----
  attn_mfma<<<1024, dim3(512), 0, stream>>>(QB, ws+oINVSP,
      ws+oKM1, ws+oKV1M, ws+oKM2, ws+oKV2M, AB);

  // ---- merged fused interp+dwconv (both branches, one launch) ----
  dwconv_f2m<<<8192, blk, 0, stream>>>(V1G, V2G, Wdwc, bdwc, AB);

  // ---- single fused projection: out = AB @ Wproj^T + bproj ----
  gmfma<128,128,0,1,0><<<dim3(512,2), blk, 0, stream>>>(AB, WPROJB, bproj, out, 65536, 256, 512, 512);
}